// Round 11
// baseline (113.401 us; speedup 1.0000x reference)
//
#include <hip/hip_runtime.h>

#define T 512
#define B 2
#define NH 16
#define FD 16
#define HD 64
#define DP 160
#define CH 64
#define NC 8

typedef __attribute__((ext_vector_type(4))) short short4v;
typedef __attribute__((ext_vector_type(8))) short bf16x8;
typedef __attribute__((ext_vector_type(4))) float f32x4;
typedef unsigned long long u64;

__constant__ unsigned char c_iu[120] = {
0,0,0,0,0,0,0,0,0,0,0,0,0,0,0,
1,1,1,1,1,1,1,1,1,1,1,1,1,1,
2,2,2,2,2,2,2,2,2,2,2,2,2,
3,3,3,3,3,3,3,3,3,3,3,3,
4,4,4,4,4,4,4,4,4,4,4,
5,5,5,5,5,5,5,5,5,5,
6,6,6,6,6,6,6,6,6,
7,7,7,7,7,7,7,7,
8,8,8,8,8,8,8,
9,9,9,9,9,9,
10,10,10,10,10,
11,11,11,11,
12,12,12,
13,13,
14};
__constant__ unsigned char c_ju[120] = {
1,2,3,4,5,6,7,8,9,10,11,12,13,14,15,
2,3,4,5,6,7,8,9,10,11,12,13,14,15,
3,4,5,6,7,8,9,10,11,12,13,14,15,
4,5,6,7,8,9,10,11,12,13,14,15,
5,6,7,8,9,10,11,12,13,14,15,
6,7,8,9,10,11,12,13,14,15,
7,8,9,10,11,12,13,14,15,
8,9,10,11,12,13,14,15,
9,10,11,12,13,14,15,
10,11,12,13,14,15,
11,12,13,14,15,
12,13,14,15,
13,14,15,
14,15,
15};

__device__ inline unsigned short f2bf_rne(float x) {
    unsigned u = __float_as_uint(x);
    u += 0x7fff + ((u >> 16) & 1);
    return (unsigned short)(u >> 16);
}
__device__ inline float bf2f(unsigned short h) {
    return __uint_as_float(((unsigned)h) << 16);
}
__device__ inline f32x4 mfma1(bf16x8 a, bf16x8 b, f32x4 acc) {
    return __builtin_amdgcn_mfma_f32_16x16x32_bf16(a, b, acc, 0, 0, 0);
}
__device__ inline bf16x8 cvt8(float4 a, float4 b) {
    bf16x8 r;
    r[0]=(short)f2bf_rne(a.x); r[1]=(short)f2bf_rne(a.y);
    r[2]=(short)f2bf_rne(a.z); r[3]=(short)f2bf_rne(a.w);
    r[4]=(short)f2bf_rne(b.x); r[5]=(short)f2bf_rne(b.y);
    r[6]=(short)f2bf_rne(b.z); r[7]=(short)f2bf_rne(b.w);
    return r;
}
// Taylor feature value for index D from x[16] (exact same formula/rounding).
__device__ inline float featval(const float* __restrict__ x, int D) {
    if (D == 0)       return 1.f;
    else if (D < 17)  return x[D-1] * 0.5f;
    else if (D < 33)  { float a = x[D-17]; return a * a * 0.17677669529663687f; }
    else if (D < 153) { int p = D - 33; return x[c_iu[p]] * x[c_ju[p]] * 0.25f; }
    return 0.f;
}

// ---- Coherent WRITE path (sc1 / MALL write-through). Reads cached (R6-R10).
__device__ inline void st_coh_u32(unsigned* p, unsigned v) {
    __hip_atomic_store(p, v, __ATOMIC_RELAXED, __HIP_MEMORY_SCOPE_AGENT);
}
__device__ inline unsigned ld_coh_u32(const unsigned* p) {
    return __hip_atomic_load((unsigned*)p, __ATOMIC_RELAXED, __HIP_MEMORY_SCOPE_AGENT);
}
// Quad-pack store: 4 consecutive lanes fold bf16 cols into one u64 store.
__device__ inline void st_quad(short* pbase, unsigned short v, int lane) {
    unsigned x = v;
    unsigned o1 = (unsigned)__shfl_xor((int)x, 1);
    unsigned lo = ((lane & 1) == 0) ? (x | (o1 << 16)) : (o1 | (x << 16));
    unsigned o2 = (unsigned)__shfl_xor((int)lo, 2);
    if ((lane & 3) == 0) {
        u64 q = (u64)lo | ((u64)o2 << 32);
        __hip_atomic_store((u64*)pbase, q, __ATOMIC_RELAXED, __HIP_MEMORY_SCOPE_AGENT);
    }
}

// ---- Producer-group sync (R10-proven): no cache maintenance anywhere.
__device__ inline void group_arrive(unsigned* cnt) {
    __builtin_amdgcn_s_waitcnt(0);     // all prior sc1 stores reached MALL
    __syncthreads();                   // every wave of the block drained
    if (threadIdx.x == 0)
        __hip_atomic_fetch_add(cnt, 1u, __ATOMIC_RELAXED, __HIP_MEMORY_SCOPE_AGENT);
}
__device__ inline void group_wait(const unsigned* cnt, unsigned tgt) {
    if (threadIdx.x == 0) {
        for (unsigned it = 0; it < (1u << 17); ++it) {   // bounded: no hang
            if (ld_coh_u32(cnt) >= tgt) break;
            __builtin_amdgcn_s_sleep(2);
        }
    }
    __syncthreads();
}

// Writeback+invalidate all XCD L2s before fused (harness poison-fill residue).
__global__ void wsflush() {
    if (threadIdx.x == 0) __builtin_amdgcn_fence(__ATOMIC_SEQ_CST, "agent");
}
// Zero the 64 counter slots (16 Cp-stripe + 32 bh + 16 Y-stripe).
__global__ void barinit(unsigned* __restrict__ bar) {
    st_coh_u32(&bar[threadIdx.x * 16], 0u);
}

// ============================================================================
// FUSED persistent kernel (R10 body + R11 XCD-rectangle swizzle):
// 256 blocks x 1024 threads, group-counter sync (no full-grid barriers).
// R11 delta: phases 1 & 4 map (bm,bn) so each XCD (bid%8) owns an 8bm x 4bn
// rectangle: A/Y stripes duplicated x4 (was x8), W columns x2 (was x1)
// -> net fetch 38->28 MB (phase 1), 20->16 MB (phase 4). Pure index remap:
// bijective on (bm,bn), counters still get 16 arrivals/stripe, arithmetic
// identical (bit-identical output).
// ============================================================================
__global__ __launch_bounds__(1024)
void fused(const float* __restrict__ hs, const float* __restrict__ Wq,
           const float* __restrict__ Wk, const float* __restrict__ Wv,
           const float* __restrict__ Wo,
           short* __restrict__ Cp, short* __restrict__ S, float* __restrict__ Z,
           short* __restrict__ Y, float* __restrict__ out,
           unsigned* __restrict__ bar) {
    __shared__ __align__(16) char smem[116736];
    const int tid = threadIdx.x;
    const int bid = blockIdx.x;
    const int lane = tid & 63;
    const int w = tid >> 6;                  // wave 0..15
    const int fm = lane & 15, fk = (lane >> 4) * 8;
    const int crow0 = (lane >> 4) * 4, ccol = lane & 15;

    // XCD-rectangle remap for GEMM phases: XCD g owns 8bm x 4bn tiles.
    const int g1 = bid & 7, i1 = bid >> 3;
    const int tm = ((g1 & 1) << 3) + (i1 & 7);         // bm tile 0..15
    const int tn = ((g1 >> 1) << 2) + (i1 >> 3);       // bn tile 0..15

    // phase-2/3 identity and its producer stripe
    const int bh23 = bid & 31, c23 = bid >> 5;
    const int strp23 = ((bh23 >> 4) << 3) + c23;       // b*8 + c

    // ---------------- phase 1: gemm_proj  Cp = bf16(hs) @ bf16(W)^T ----------
    {
        short (*sA)[2][64][72] = (short(*)[2][64][72])(smem);            // 36864
        short (*sB)[2][96][72] = (short(*)[2][96][72])(smem + 36864);    // 55296
        float (*sRed)[12]      = (float(*)[12])(smem + 92160);          // 24576
        const int half = tid >> 9;
        const int ht = tid & 511;
        const int wh = w & 7;
        const int bm = tm * 64, bn = tn * 96;
        const int wm = (wh & 3) * 16, wn = (wh >> 2) * 48;
        const int srA = ht >> 3, skA = (ht & 7) * 8;       // 8 shorts/thread
        const int srB = ht >> 2, skB = (ht & 3) * 16;      // 16 shorts/thread
        const int kbase = half * 512;
        f32x4 acc[3] = {};
        const float* pA = hs + (size_t)(bm + srA) * 1024 + kbase + skA;
        const int Rb = bn + (ht < 384 ? srB : 0);
        const float* wsrc = (Rb < 256) ? (Wq + (size_t)Rb * 1024)
                          : (Rb < 512) ? (Wk + (size_t)(Rb - 256) * 1024)
                                       : (Wv + (size_t)(Rb - 512) * 1024);
        const float* pB = wsrc + kbase + skB;
        float4 qa0, qa1, qb0, qb1, qb2, qb3;
        qa0 = *(const float4*)pA; qa1 = *(const float4*)(pA + 4);
        if (ht < 384) {
            qb0 = *(const float4*)pB;        qb1 = *(const float4*)(pB + 4);
            qb2 = *(const float4*)(pB + 8);  qb3 = *(const float4*)(pB + 12);
        }
        *(bf16x8*)&sA[half][0][srA][skA] = cvt8(qa0, qa1);
        if (ht < 384) {
            *(bf16x8*)&sB[half][0][srB][skB]     = cvt8(qb0, qb1);
            *(bf16x8*)&sB[half][0][srB][skB + 8] = cvt8(qb2, qb3);
        }
        qa0 = *(const float4*)(pA + 64); qa1 = *(const float4*)(pA + 68);
        if (ht < 384) {
            qb0 = *(const float4*)(pB + 64); qb1 = *(const float4*)(pB + 68);
            qb2 = *(const float4*)(pB + 72); qb3 = *(const float4*)(pB + 76);
        }
        __syncthreads();
        for (int k0 = 0; k0 < 512; k0 += 64) {
            const int bb = (k0 >> 6) & 1;
            bf16x8 a[2], bfr[2][3];
            #pragma unroll
            for (int ks = 0; ks < 2; ++ks) {
                a[ks] = *(const bf16x8*)&sA[half][bb][wm + fm][ks*32 + fk];
                #pragma unroll
                for (int j = 0; j < 3; ++j)
                    bfr[ks][j] = *(const bf16x8*)&sB[half][bb][wn + j*16 + fm][ks*32 + fk];
            }
            if (k0 + 64 < 512) {
                *(bf16x8*)&sA[half][bb^1][srA][skA] = cvt8(qa0, qa1);
                if (ht < 384) {
                    *(bf16x8*)&sB[half][bb^1][srB][skB]     = cvt8(qb0, qb1);
                    *(bf16x8*)&sB[half][bb^1][srB][skB + 8] = cvt8(qb2, qb3);
                }
            }
            if (k0 + 128 < 512) {
                const float* pA2 = pA + k0 + 128;
                qa0 = *(const float4*)pA2; qa1 = *(const float4*)(pA2 + 4);
                if (ht < 384) {
                    const float* pB2 = pB + k0 + 128;
                    qb0 = *(const float4*)pB2;       qb1 = *(const float4*)(pB2 + 4);
                    qb2 = *(const float4*)(pB2 + 8); qb3 = *(const float4*)(pB2 + 12);
                }
            }
            #pragma unroll
            for (int ks = 0; ks < 2; ++ks)
                #pragma unroll
                for (int j = 0; j < 3; ++j)
                    acc[j] = mfma1(a[ks], bfr[ks][j], acc[j]);
            __syncthreads();
        }
        __syncthreads();
        if (half == 1) {
            #pragma unroll
            for (int j = 0; j < 3; ++j)
                *(f32x4*)&sRed[ht][j * 4] = acc[j];
        }
        __syncthreads();
        if (half == 0) {
            #pragma unroll
            for (int j = 0; j < 3; ++j) {
                f32x4 o = acc[j];
                f32x4 p = *(const f32x4*)&sRed[ht][j * 4];
                #pragma unroll
                for (int r = 0; r < 4; ++r) {
                    short* pcol = Cp + (size_t)(bm + wm + crow0 + r) * 1536
                                     + bn + wn + j*16 + (ccol & ~3);
                    st_quad(pcol, f2bf_rne(o[r] + p[r]), lane);
                }
            }
        }
    }
    group_arrive(&bar[tm * 16]);                       // c1[bm]: stripe done
    group_wait(&bar[strp23 * 16], 16u);                // need Cp stripe b*8+c

    // ---------------- phase 2: chunk_state -----------------------------------
    {
        float (*sKP)[17]          = (float(*)[17])(smem);
        unsigned short (*sKT)[72] = (unsigned short(*)[72])(smem + 4352);
        unsigned short (*sVT)[72] = (unsigned short(*)[72])(smem + 27392);
        const int bh = bh23, c = c23;
        const int b = bh >> 4, h = bh & 15;
        const int wm = (w & 3) * 16, wn = (w >> 2) * 80;   // valid for w<8
        const int r = (tid & 255) >> 2, q4 = tid & 3;
        const size_t rowbase = (size_t)(b*T + c*CH + r) * 1536;
        if (tid < 256) {
            short4v kv = *(const short4v*)(Cp + rowbase + 256 + h*16 + q4*4);
            const short* pv = Cp + rowbase + 512 + h*HD + q4*16;
            bf16x8 v0 = *(const bf16x8*)pv, v1 = *(const bf16x8*)(pv + 8);
            float4 kf;
            kf.x = bf2f((unsigned short)kv[0]); kf.y = bf2f((unsigned short)kv[1]);
            kf.z = bf2f((unsigned short)kv[2]); kf.w = bf2f((unsigned short)kv[3]);
            *(float4*)&sKP[r][q4*4] = kf;
            #pragma unroll
            for (int e = 0; e < 8; ++e) {
                sVT[q4*16 + e][r]     = (unsigned short)v0[e];
                sVT[q4*16 + 8 + e][r] = (unsigned short)v1[e];
            }
        }
        __syncthreads();
        {   // transposed features, 4x parallel
            const int r3 = tid >> 4, sub = tid & 15;
            const int q4t = sub & 3, gh = sub >> 2;
            const float* x = sKP[r3];
            #pragma unroll
            for (int dd = 0; dd < 10; ++dd) {
                const int D = q4t*40 + gh*10 + dd;
                sKT[D][r3] = f2bf_rne(featval(x, D));
            }
        }
        __syncthreads();
        if (tid < DP) {
            float zz = 0.f;
            #pragma unroll
            for (int blk = 0; blk < 8; ++blk) {
                bf16x8 v = *(const bf16x8*)&sKT[tid][blk*8];
                #pragma unroll
                for (int e = 0; e < 8; ++e) zz += bf2f((unsigned short)v[e]);
            }
            st_coh_u32((unsigned*)(Z + ((size_t)(bh*NC + c)) * DP + tid),
                       __float_as_uint(zz));
        }
        if (w < 8) {
            f32x4 acc2[5] = {};
            #pragma unroll
            for (int k0 = 0; k0 < 64; k0 += 32) {
                bf16x8 a = *(const bf16x8*)&sVT[wm + fm][k0 + fk];
                #pragma unroll
                for (int j = 0; j < 5; ++j) {
                    bf16x8 bv = *(const bf16x8*)&sKT[wn + j*16 + fm][k0 + fk];
                    acc2[j] = mfma1(a, bv, acc2[j]);
                }
            }
            short* Sb = S + ((size_t)(bh*NC + c)) * CH * DP;
            #pragma unroll
            for (int j = 0; j < 5; ++j)
                #pragma unroll
                for (int rr = 0; rr < 4; ++rr) {
                    short* pcol = Sb + (size_t)(wm + crow0 + rr) * DP
                                     + wn + j*16 + (ccol & ~3);
                    st_quad(pcol, f2bf_rne(acc2[j][rr]), lane);
                }
        }
    }
    group_arrive(&bar[(16 + bh23) * 16]);              // c2[bh]: S/Z chunk done
    group_wait(&bar[(16 + bh23) * 16], 8u);            // need all 8 chunks of bh

    // ---------------- phase 3: chunk_out -------------------------------------
    {
        float (*sQP)[17]          = (float(*)[17])(smem);
        float (*sKP)[17]          = (float(*)[17])(smem + 4352);
        unsigned short (*sQf)[168]= (unsigned short(*)[168])(smem + 8704);
        unsigned short (*sKf)[168]= (unsigned short(*)[168])(smem + 30208);
        unsigned short (*sPb)[168]= (unsigned short(*)[168])(smem + 51712);
        unsigned short (*sAb)[72] = (unsigned short(*)[72])(smem + 73216);
        unsigned short (*sVT)[72] = (unsigned short(*)[72])(smem + 82432);
        float* sZp  = (float*)(smem + 91648);
        float* sDen = (float*)(smem + 92288);
        const int bh = bh23, c = c23;
        const int b = bh >> 4, h = bh & 15;
        const int wm = (w & 3) * 16, wn = (w >> 2) * 16;
        const int r = (tid & 255) >> 2, q4 = tid & 3;
        const size_t rowbase = (size_t)(b*T + c*CH + r) * 1536;
        f32x4 accA = {}, accI = {};
        if (tid < 256) {
            short4v qv = *(const short4v*)(Cp + rowbase + h*16 + q4*4);
            short4v kv = *(const short4v*)(Cp + rowbase + 256 + h*16 + q4*4);
            const short* pv = Cp + rowbase + 512 + h*HD + q4*16;
            bf16x8 v0 = *(const bf16x8*)pv, v1 = *(const bf16x8*)(pv + 8);
            float4 qf, kf;
            qf.x = bf2f((unsigned short)qv[0]); qf.y = bf2f((unsigned short)qv[1]);
            qf.z = bf2f((unsigned short)qv[2]); qf.w = bf2f((unsigned short)qv[3]);
            kf.x = bf2f((unsigned short)kv[0]); kf.y = bf2f((unsigned short)kv[1]);
            kf.z = bf2f((unsigned short)kv[2]); kf.w = bf2f((unsigned short)kv[3]);
            *(float4*)&sQP[r][q4*4] = qf;
            *(float4*)&sKP[r][q4*4] = kf;
            #pragma unroll
            for (int e = 0; e < 8; ++e) {
                sVT[q4*16 + e][r]     = (unsigned short)v0[e];
                sVT[q4*16 + 8 + e][r] = (unsigned short)v1[e];
            }
            if (tid < DP) {
                // Z-prefix: all 7 loads unconditional (c2[bh]==8 -> race-free),
                // value-masked accumulate.
                float zv[7];
                #pragma unroll
                for (int cc = 0; cc < 7; ++cc)
                    zv[cc] = Z[((size_t)(bh*NC + cc)) * DP + tid];
                float zz = 0.f;
                #pragma unroll
                for (int cc = 0; cc < 7; ++cc)
                    zz += (cc < c) ? zv[cc] : 0.f;
                sZp[tid] = zz;
            }
        }
        __syncthreads();
        {   // row-major features: sub = dst*8 + q4f*2 + gh
            const int r3 = tid >> 4, sub = tid & 15;
            const int dst = sub >> 3, q4f = (sub >> 1) & 3, gh = sub & 1;
            const float* x = dst ? sKP[r3] : sQP[r3];
            unsigned short* drow = dst ? sKf[r3] : sQf[r3];
            #pragma unroll
            for (int g = 0; g < 5; ++g) {
                const int gg = gh*5 + g;
                short4v s;
                #pragma unroll
                for (int e = 0; e < 4; ++e)
                    s[e] = (short)f2bf_rne(featval(x, q4f*40 + gg*4 + e));
                *(short4v*)(drow + q4f*40 + gg*4) = s;
            }
        }
        {   // S-prefix sums, 1024 threads, unconditional 7-load batches.
            for (int e = tid; e < 1280; e += 1024) {
                const int d = e / 20, D8 = (e % 20) * 8;
                bf16x8 raw[7];
                #pragma unroll
                for (int cc = 0; cc < 7; ++cc)
                    raw[cc] = *(const bf16x8*)(S + (((size_t)(bh*NC + cc)) * CH + d) * DP + D8);
                float a8[8] = {};
                #pragma unroll
                for (int cc = 0; cc < 7; ++cc) {
                    #pragma unroll
                    for (int e2 = 0; e2 < 8; ++e2)
                        a8[e2] += (cc < c) ? bf2f((unsigned short)raw[cc][e2]) : 0.f;
                }
                bf16x8 o;
                #pragma unroll
                for (int e2 = 0; e2 < 8; ++e2) o[e2] = (short)f2bf_rne(a8[e2]);
                *(bf16x8*)&sPb[d][D8] = o;
            }
        }
        __syncthreads();
        {   // MFMA stage 1: A = Qf.Kf^T, I = Qf.Pb^T
            for (int k0 = 0; k0 < DP; k0 += 32) {
                bf16x8 qv = *(const bf16x8*)&sQf[wm + fm][k0 + fk];
                bf16x8 kv = *(const bf16x8*)&sKf[wn + fm][k0 + fk];
                bf16x8 pv = *(const bf16x8*)&sPb[wn + fm][k0 + fk];
                accA = mfma1(qv, kv, accA);
                accI = mfma1(qv, pv, accI);
            }
        }
        if (tid < 256) {   // denominator dot with Z-prefix
            float dp = 0.f;
            #pragma unroll
            for (int g = 0; g < 5; ++g) {
                bf16x8 v = *(const bf16x8*)&sQf[r][q4*40 + g*8];
                #pragma unroll
                for (int e = 0; e < 8; ++e)
                    dp += bf2f((unsigned short)v[e]) * sZp[q4*40 + g*8 + e];
            }
            dp += __shfl_xor(dp, 1);
            dp += __shfl_xor(dp, 2);
            if (q4 == 0) sDen[r] = dp;
        }
        {   // causal-mask A into LDS (each wave its 16x16 tile)
            #pragma unroll
            for (int rr = 0; rr < 4; ++rr) {
                const int t_ = wm + crow0 + rr, s_ = wn + ccol;
                sAb[t_][s_] = (s_ <= t_) ? f2bf_rne(accA[rr]) : 0;
            }
        }
        __syncthreads();
        if (tid < 256) {   // row-sum of causal A into denominator
            float rs = 0.f;
            bf16x8 v0 = *(const bf16x8*)&sAb[r][q4*16];
            bf16x8 v1 = *(const bf16x8*)&sAb[r][q4*16 + 8];
            #pragma unroll
            for (int e = 0; e < 8; ++e)
                rs += bf2f((unsigned short)v0[e]) + bf2f((unsigned short)v1[e]);
            rs += __shfl_xor(rs, 1);
            rs += __shfl_xor(rs, 2);
            if (q4 == 0) sDen[r] += rs;
        }
        __syncthreads();
        {   // MFMA stage 2: I += Ab.VT^T ; write Y
            #pragma unroll
            for (int k0 = 0; k0 < 64; k0 += 32) {
                bf16x8 a = *(const bf16x8*)&sAb[wm + fm][k0 + fk];
                bf16x8 bv = *(const bf16x8*)&sVT[wn + fm][k0 + fk];
                accI = mfma1(a, bv, accI);
            }
            #pragma unroll
            for (int rr = 0; rr < 4; ++rr) {
                const int t_ = wm + crow0 + rr;
                const float inv = 1.f / (sDen[t_] + 1e-12f);
                const size_t grow = (size_t)(b*T + c*CH + t_) * 1024 + h*HD;
                short* pcol = Y + grow + wn + (ccol & ~3);
                st_quad(pcol, f2bf_rne(accI[rr] * inv), lane);
            }
        }
    }
    group_arrive(&bar[(48 + strp23) * 16]);            // c3[stripe]: Y rows done
    // phase-4 Wo prefetch: pure input, load BEFORE the wait; completes during spin.
    const int p4_half = tid >> 9;
    const int p4_ht = tid & 511;
    const int p4_bn = tn * 64;
    const int p4_srow = p4_ht >> 3, p4_skq = (p4_ht & 7) * 8;
    const float* p4_pB = Wo + (size_t)(p4_bn + p4_srow) * 1024 + p4_half * 512 + p4_skq;
    float4 p4_qb0 = *(const float4*)p4_pB;
    float4 p4_qb1 = *(const float4*)(p4_pB + 4);
    group_wait(&bar[(48 + tm) * 16], 16u);             // need Y stripe tm

    // ---------------- phase 4: gemm_out  out = Y @ bf16(Wo)^T ----------------
    {
        short (*sA)[2][64][72] = (short(*)[2][64][72])(smem);
        short (*sB)[2][64][72] = (short(*)[2][64][72])(smem + 36864);
        float (*sRed)[8]       = (float(*)[8])(smem + 73728);           // 16384
        const int half = p4_half;
        const int ht = p4_ht;
        const int wh = w & 7;
        const int bm = tm * 64, bn = p4_bn;
        const int wm = (wh & 3) * 16, wn = (wh >> 2) * 32;
        const int srow = p4_srow, skq = p4_skq;
        const int kbase = half * 512;
        f32x4 acc[2] = {};
        const short* pA = Y + (size_t)(bm + srow) * 1024 + kbase + skq;
        const float* pB = p4_pB;
        bf16x8 va;
        float4 qb0 = p4_qb0, qb1 = p4_qb1;
        va = *(const bf16x8*)pA;
        *(bf16x8*)&sA[half][0][srow][skq] = va;
        *(bf16x8*)&sB[half][0][srow][skq] = cvt8(qb0, qb1);
        va = *(const bf16x8*)(pA + 64);
        qb0 = *(const float4*)(pB + 64); qb1 = *(const float4*)(pB + 68);
        __syncthreads();
        for (int k0 = 0; k0 < 512; k0 += 64) {
            const int bb = (k0 >> 6) & 1;
            bf16x8 a[2], b2[2][2];
            #pragma unroll
            for (int ks = 0; ks < 2; ++ks) {
                a[ks] = *(const bf16x8*)&sA[half][bb][wm + fm][ks*32 + fk];
                #pragma unroll
                for (int j = 0; j < 2; ++j)
                    b2[ks][j] = *(const bf16x8*)&sB[half][bb][wn + j*16 + fm][ks*32 + fk];
            }
            if (k0 + 64 < 512) {
                *(bf16x8*)&sA[half][bb^1][srow][skq] = va;
                *(bf16x8*)&sB[half][bb^1][srow][skq] = cvt8(qb0, qb1);
            }
            if (k0 + 128 < 512) {
                va = *(const bf16x8*)(pA + k0 + 128);
                const float* pB2 = pB + k0 + 128;
                qb0 = *(const float4*)pB2; qb1 = *(const float4*)(pB2 + 4);
            }
            #pragma unroll
            for (int ks = 0; ks < 2; ++ks)
                #pragma unroll
                for (int j = 0; j < 2; ++j)
                    acc[j] = mfma1(a[ks], b2[ks][j], acc[j]);
            __syncthreads();
        }
        __syncthreads();
        if (half == 1) {
            #pragma unroll
            for (int j = 0; j < 2; ++j)
                *(f32x4*)&sRed[ht][j * 4] = acc[j];
        }
        __syncthreads();
        if (half == 0) {
            #pragma unroll
            for (int j = 0; j < 2; ++j) {
                f32x4 p = *(const f32x4*)&sRed[ht][j * 4];
                #pragma unroll
                for (int r = 0; r < 4; ++r)
                    out[(size_t)(bm + wm + crow0 + r) * 1024 + bn + wn + j*16 + ccol] =
                        acc[j][r] + p[r];
            }
        }
    }
}

extern "C" void kernel_launch(void* const* d_in, const int* in_sizes, int n_in,
                              void* d_out, int out_size, void* d_ws, size_t ws_size,
                              hipStream_t stream) {
    const float* hs = (const float*)d_in[0];
    const float* Wq = (const float*)d_in[1];
    const float* Wk = (const float*)d_in[2];
    const float* Wv = (const float*)d_in[3];
    const float* Wo = (const float*)d_in[4];
    float* out = (float*)d_out;

    char* p = (char*)d_ws;
    short* Cp  = (short*)p; p += (size_t)1024*1536*2;
    short* S   = (short*)p; p += (size_t)32*NC*CH*DP*2;
    float* Z   = (float*)p; p += (size_t)32*NC*DP*4;
    short* Y   = (short*)p; p += (size_t)1048576*2;
    unsigned* bar = (unsigned*)p; p += 4096;

    wsflush<<<dim3(64), dim3(64), 0, stream>>>();
    barinit<<<dim3(1), dim3(64), 0, stream>>>(bar);
    fused<<<dim3(256), dim3(1024), 0, stream>>>(hs, Wq, Wk, Wv, Wo,
                                                Cp, S, Z, Y, out, bar);
}

// Round 12
// 112.292 us; speedup vs baseline: 1.0099x; 1.0099x over previous
//
#include <hip/hip_runtime.h>

#define T 512
#define B 2
#define NH 16
#define FD 16
#define HD 64
#define DP 160
#define CH 64
#define NC 8

typedef __attribute__((ext_vector_type(4))) short short4v;
typedef __attribute__((ext_vector_type(8))) short bf16x8;
typedef __attribute__((ext_vector_type(4))) float f32x4;
typedef unsigned long long u64;

__constant__ unsigned char c_iu[120] = {
0,0,0,0,0,0,0,0,0,0,0,0,0,0,0,
1,1,1,1,1,1,1,1,1,1,1,1,1,1,
2,2,2,2,2,2,2,2,2,2,2,2,2,
3,3,3,3,3,3,3,3,3,3,3,3,
4,4,4,4,4,4,4,4,4,4,4,
5,5,5,5,5,5,5,5,5,5,
6,6,6,6,6,6,6,6,6,
7,7,7,7,7,7,7,7,
8,8,8,8,8,8,8,
9,9,9,9,9,9,
10,10,10,10,10,
11,11,11,11,
12,12,12,
13,13,
14};
__constant__ unsigned char c_ju[120] = {
1,2,3,4,5,6,7,8,9,10,11,12,13,14,15,
2,3,4,5,6,7,8,9,10,11,12,13,14,15,
3,4,5,6,7,8,9,10,11,12,13,14,15,
4,5,6,7,8,9,10,11,12,13,14,15,
5,6,7,8,9,10,11,12,13,14,15,
6,7,8,9,10,11,12,13,14,15,
7,8,9,10,11,12,13,14,15,
8,9,10,11,12,13,14,15,
9,10,11,12,13,14,15,
10,11,12,13,14,15,
11,12,13,14,15,
12,13,14,15,
13,14,15,
14,15,
15};

__device__ inline unsigned short f2bf_rne(float x) {
    unsigned u = __float_as_uint(x);
    u += 0x7fff + ((u >> 16) & 1);
    return (unsigned short)(u >> 16);
}
__device__ inline float bf2f(unsigned short h) {
    return __uint_as_float(((unsigned)h) << 16);
}
__device__ inline f32x4 mfma1(bf16x8 a, bf16x8 b, f32x4 acc) {
    return __builtin_amdgcn_mfma_f32_16x16x32_bf16(a, b, acc, 0, 0, 0);
}
__device__ inline bf16x8 cvt8(float4 a, float4 b) {
    bf16x8 r;
    r[0]=(short)f2bf_rne(a.x); r[1]=(short)f2bf_rne(a.y);
    r[2]=(short)f2bf_rne(a.z); r[3]=(short)f2bf_rne(a.w);
    r[4]=(short)f2bf_rne(b.x); r[5]=(short)f2bf_rne(b.y);
    r[6]=(short)f2bf_rne(b.z); r[7]=(short)f2bf_rne(b.w);
    return r;
}
// Taylor feature value for index D from x[16] (exact same formula/rounding).
__device__ inline float featval(const float* __restrict__ x, int D) {
    if (D == 0)       return 1.f;
    else if (D < 17)  return x[D-1] * 0.5f;
    else if (D < 33)  { float a = x[D-17]; return a * a * 0.17677669529663687f; }
    else if (D < 153) { int p = D - 33; return x[c_iu[p]] * x[c_ju[p]] * 0.25f; }
    return 0.f;
}

// ---- Coherent WRITE path (sc1 / MALL write-through). Reads cached (R6-R11).
__device__ inline void st_coh_u32(unsigned* p, unsigned v) {
    __hip_atomic_store(p, v, __ATOMIC_RELAXED, __HIP_MEMORY_SCOPE_AGENT);
}
__device__ inline unsigned ld_coh_u32(const unsigned* p) {
    return __hip_atomic_load((unsigned*)p, __ATOMIC_RELAXED, __HIP_MEMORY_SCOPE_AGENT);
}
// Quad-pack store: 4 consecutive lanes fold bf16 cols into one u64 store.
__device__ inline void st_quad(short* pbase, unsigned short v, int lane) {
    unsigned x = v;
    unsigned o1 = (unsigned)__shfl_xor((int)x, 1);
    unsigned lo = ((lane & 1) == 0) ? (x | (o1 << 16)) : (o1 | (x << 16));
    unsigned o2 = (unsigned)__shfl_xor((int)lo, 2);
    if ((lane & 3) == 0) {
        u64 q = (u64)lo | ((u64)o2 << 32);
        __hip_atomic_store((u64*)pbase, q, __ATOMIC_RELAXED, __HIP_MEMORY_SCOPE_AGENT);
    }
}

// ---- Producer-group sync (R10-proven): no cache maintenance anywhere.
__device__ inline void group_arrive(unsigned* cnt) {
    __builtin_amdgcn_s_waitcnt(0);     // all prior sc1 stores reached MALL
    __syncthreads();                   // every wave of the block drained
    if (threadIdx.x == 0)
        __hip_atomic_fetch_add(cnt, 1u, __ATOMIC_RELAXED, __HIP_MEMORY_SCOPE_AGENT);
}
__device__ inline void group_wait(const unsigned* cnt, unsigned tgt) {
    if (threadIdx.x == 0) {
        for (unsigned it = 0; it < (1u << 17); ++it) {   // bounded: no hang
            if (ld_coh_u32(cnt) >= tgt) break;
            __builtin_amdgcn_s_sleep(2);
        }
    }
    __syncthreads();
}

// Writeback+invalidate all XCD L2s before fused (harness poison-fill residue).
__global__ void wsflush() {
    if (threadIdx.x == 0) __builtin_amdgcn_fence(__ATOMIC_SEQ_CST, "agent");
}
// Zero the 64 counter slots (16 Cp-stripe + 32 bh + 16 Y-stripe).
__global__ void barinit(unsigned* __restrict__ bar) {
    st_coh_u32(&bar[threadIdx.x * 16], 0u);
}

// ============================================================================
// FUSED persistent kernel (R11 body + R12 2-deep GEMM prefetch):
// 256 blocks x 1024 threads, group-counter sync, XCD-rectangle swizzle.
// R12 delta: phases 1 & 4 use TWO register prefetch sets (A/B), giving a
// load->LDS-write distance of 2 K-steps (~600-800 cy cover vs L3/MALL
// latency). LDS stays double-buffered; MFMA order identical -> bit-identical.
// Phase-4: all 3 Wo chunks prefetched pre-wait; 3 Y chunks issued together.
// ============================================================================
__global__ __launch_bounds__(1024)
void fused(const float* __restrict__ hs, const float* __restrict__ Wq,
           const float* __restrict__ Wk, const float* __restrict__ Wv,
           const float* __restrict__ Wo,
           short* __restrict__ Cp, short* __restrict__ S, float* __restrict__ Z,
           short* __restrict__ Y, float* __restrict__ out,
           unsigned* __restrict__ bar) {
    __shared__ __align__(16) char smem[116736];
    const int tid = threadIdx.x;
    const int bid = blockIdx.x;
    const int lane = tid & 63;
    const int w = tid >> 6;                  // wave 0..15
    const int fm = lane & 15, fk = (lane >> 4) * 8;
    const int crow0 = (lane >> 4) * 4, ccol = lane & 15;

    // XCD-rectangle remap for GEMM phases: XCD g owns 8bm x 4bn tiles.
    const int g1 = bid & 7, i1 = bid >> 3;
    const int tm = ((g1 & 1) << 3) + (i1 & 7);         // bm tile 0..15
    const int tn = ((g1 >> 1) << 2) + (i1 >> 3);       // bn tile 0..15

    // phase-2/3 identity and its producer stripe
    const int bh23 = bid & 31, c23 = bid >> 5;
    const int strp23 = ((bh23 >> 4) << 3) + c23;       // b*8 + c

    // ---------------- phase 1: gemm_proj  Cp = bf16(hs) @ bf16(W)^T ----------
    {
        short (*sA)[2][64][72] = (short(*)[2][64][72])(smem);            // 36864
        short (*sB)[2][96][72] = (short(*)[2][96][72])(smem + 36864);    // 55296
        float (*sRed)[12]      = (float(*)[12])(smem + 92160);          // 24576
        const int half = tid >> 9;
        const int ht = tid & 511;
        const int wh = w & 7;
        const int bm = tm * 64, bn = tn * 96;
        const int wm = (wh & 3) * 16, wn = (wh >> 2) * 48;
        const int srA = ht >> 3, skA = (ht & 7) * 8;       // 8 shorts/thread
        const int srB = ht >> 2, skB = (ht & 3) * 16;      // 16 shorts/thread
        const int kbase = half * 512;
        f32x4 acc[3] = {};
        const float* pA = hs + (size_t)(bm + srA) * 1024 + kbase + skA;
        const int Rb = bn + (ht < 384 ? srB : 0);
        const float* wsrc = (Rb < 256) ? (Wq + (size_t)Rb * 1024)
                          : (Rb < 512) ? (Wk + (size_t)(Rb - 256) * 1024)
                                       : (Wv + (size_t)(Rb - 512) * 1024);
        const float* pB = wsrc + kbase + skB;
        // --- stage 0 direct to LDS
        {
            float4 t0 = *(const float4*)pA, t1 = *(const float4*)(pA + 4);
            float4 u0, u1, u2, u3;
            if (ht < 384) {
                u0 = *(const float4*)pB;        u1 = *(const float4*)(pB + 4);
                u2 = *(const float4*)(pB + 8);  u3 = *(const float4*)(pB + 12);
            }
            *(bf16x8*)&sA[half][0][srA][skA] = cvt8(t0, t1);
            if (ht < 384) {
                *(bf16x8*)&sB[half][0][srB][skB]     = cvt8(u0, u1);
                *(bf16x8*)&sB[half][0][srB][skB + 8] = cvt8(u2, u3);
            }
        }
        // --- prefetch set A (data[64]) and set B (data[128])
        float4 aA0, aA1, bA0, bA1, bA2, bA3;
        float4 aB0, aB1, bB0, bB1, bB2, bB3;
        aA0 = *(const float4*)(pA + 64);  aA1 = *(const float4*)(pA + 68);
        aB0 = *(const float4*)(pA + 128); aB1 = *(const float4*)(pA + 132);
        if (ht < 384) {
            bA0 = *(const float4*)(pB + 64);  bA1 = *(const float4*)(pB + 68);
            bA2 = *(const float4*)(pB + 72);  bA3 = *(const float4*)(pB + 76);
            bB0 = *(const float4*)(pB + 128); bB1 = *(const float4*)(pB + 132);
            bB2 = *(const float4*)(pB + 136); bB3 = *(const float4*)(pB + 140);
        }
        __syncthreads();
        for (int k0 = 0; k0 < 512; k0 += 128) {
            // ---- sub0: consume LDS buf0 (data[k0]); stage setA -> buf1
            {
                bf16x8 a[2], bfr[2][3];
                #pragma unroll
                for (int ks = 0; ks < 2; ++ks) {
                    a[ks] = *(const bf16x8*)&sA[half][0][wm + fm][ks*32 + fk];
                    #pragma unroll
                    for (int j = 0; j < 3; ++j)
                        bfr[ks][j] = *(const bf16x8*)&sB[half][0][wn + j*16 + fm][ks*32 + fk];
                }
                *(bf16x8*)&sA[half][1][srA][skA] = cvt8(aA0, aA1);
                if (ht < 384) {
                    *(bf16x8*)&sB[half][1][srB][skB]     = cvt8(bA0, bA1);
                    *(bf16x8*)&sB[half][1][srB][skB + 8] = cvt8(bA2, bA3);
                }
                if (k0 + 192 < 512) {
                    const float* pA2 = pA + k0 + 192;
                    aA0 = *(const float4*)pA2; aA1 = *(const float4*)(pA2 + 4);
                    if (ht < 384) {
                        const float* pB2 = pB + k0 + 192;
                        bA0 = *(const float4*)pB2;       bA1 = *(const float4*)(pB2 + 4);
                        bA2 = *(const float4*)(pB2 + 8); bA3 = *(const float4*)(pB2 + 12);
                    }
                }
                #pragma unroll
                for (int ks = 0; ks < 2; ++ks)
                    #pragma unroll
                    for (int j = 0; j < 3; ++j)
                        acc[j] = mfma1(a[ks], bfr[ks][j], acc[j]);
                __syncthreads();
            }
            // ---- sub1: consume LDS buf1 (data[k0+64]); stage setB -> buf0
            {
                bf16x8 a[2], bfr[2][3];
                #pragma unroll
                for (int ks = 0; ks < 2; ++ks) {
                    a[ks] = *(const bf16x8*)&sA[half][1][wm + fm][ks*32 + fk];
                    #pragma unroll
                    for (int j = 0; j < 3; ++j)
                        bfr[ks][j] = *(const bf16x8*)&sB[half][1][wn + j*16 + fm][ks*32 + fk];
                }
                if (k0 + 128 < 512) {
                    *(bf16x8*)&sA[half][0][srA][skA] = cvt8(aB0, aB1);
                    if (ht < 384) {
                        *(bf16x8*)&sB[half][0][srB][skB]     = cvt8(bB0, bB1);
                        *(bf16x8*)&sB[half][0][srB][skB + 8] = cvt8(bB2, bB3);
                    }
                }
                if (k0 + 256 < 512) {
                    const float* pA2 = pA + k0 + 256;
                    aB0 = *(const float4*)pA2; aB1 = *(const float4*)(pA2 + 4);
                    if (ht < 384) {
                        const float* pB2 = pB + k0 + 256;
                        bB0 = *(const float4*)pB2;       bB1 = *(const float4*)(pB2 + 4);
                        bB2 = *(const float4*)(pB2 + 8); bB3 = *(const float4*)(pB2 + 12);
                    }
                }
                #pragma unroll
                for (int ks = 0; ks < 2; ++ks)
                    #pragma unroll
                    for (int j = 0; j < 3; ++j)
                        acc[j] = mfma1(a[ks], bfr[ks][j], acc[j]);
                __syncthreads();
            }
        }
        __syncthreads();
        if (half == 1) {
            #pragma unroll
            for (int j = 0; j < 3; ++j)
                *(f32x4*)&sRed[ht][j * 4] = acc[j];
        }
        __syncthreads();
        if (half == 0) {
            #pragma unroll
            for (int j = 0; j < 3; ++j) {
                f32x4 o = acc[j];
                f32x4 p = *(const f32x4*)&sRed[ht][j * 4];
                #pragma unroll
                for (int r = 0; r < 4; ++r) {
                    short* pcol = Cp + (size_t)(bm + wm + crow0 + r) * 1536
                                     + bn + wn + j*16 + (ccol & ~3);
                    st_quad(pcol, f2bf_rne(o[r] + p[r]), lane);
                }
            }
        }
    }
    group_arrive(&bar[tm * 16]);                       // c1[bm]: stripe done
    group_wait(&bar[strp23 * 16], 16u);                // need Cp stripe b*8+c

    // ---------------- phase 2: chunk_state -----------------------------------
    {
        float (*sKP)[17]          = (float(*)[17])(smem);
        unsigned short (*sKT)[72] = (unsigned short(*)[72])(smem + 4352);
        unsigned short (*sVT)[72] = (unsigned short(*)[72])(smem + 27392);
        const int bh = bh23, c = c23;
        const int b = bh >> 4, h = bh & 15;
        const int wm = (w & 3) * 16, wn = (w >> 2) * 80;   // valid for w<8
        const int r = (tid & 255) >> 2, q4 = tid & 3;
        const size_t rowbase = (size_t)(b*T + c*CH + r) * 1536;
        if (tid < 256) {
            short4v kv = *(const short4v*)(Cp + rowbase + 256 + h*16 + q4*4);
            const short* pv = Cp + rowbase + 512 + h*HD + q4*16;
            bf16x8 v0 = *(const bf16x8*)pv, v1 = *(const bf16x8*)(pv + 8);
            float4 kf;
            kf.x = bf2f((unsigned short)kv[0]); kf.y = bf2f((unsigned short)kv[1]);
            kf.z = bf2f((unsigned short)kv[2]); kf.w = bf2f((unsigned short)kv[3]);
            *(float4*)&sKP[r][q4*4] = kf;
            #pragma unroll
            for (int e = 0; e < 8; ++e) {
                sVT[q4*16 + e][r]     = (unsigned short)v0[e];
                sVT[q4*16 + 8 + e][r] = (unsigned short)v1[e];
            }
        }
        __syncthreads();
        {   // transposed features, 4x parallel
            const int r3 = tid >> 4, sub = tid & 15;
            const int q4t = sub & 3, gh = sub >> 2;
            const float* x = sKP[r3];
            #pragma unroll
            for (int dd = 0; dd < 10; ++dd) {
                const int D = q4t*40 + gh*10 + dd;
                sKT[D][r3] = f2bf_rne(featval(x, D));
            }
        }
        __syncthreads();
        if (tid < DP) {
            float zz = 0.f;
            #pragma unroll
            for (int blk = 0; blk < 8; ++blk) {
                bf16x8 v = *(const bf16x8*)&sKT[tid][blk*8];
                #pragma unroll
                for (int e = 0; e < 8; ++e) zz += bf2f((unsigned short)v[e]);
            }
            st_coh_u32((unsigned*)(Z + ((size_t)(bh*NC + c)) * DP + tid),
                       __float_as_uint(zz));
        }
        if (w < 8) {
            f32x4 acc2[5] = {};
            #pragma unroll
            for (int k0 = 0; k0 < 64; k0 += 32) {
                bf16x8 a = *(const bf16x8*)&sVT[wm + fm][k0 + fk];
                #pragma unroll
                for (int j = 0; j < 5; ++j) {
                    bf16x8 bv = *(const bf16x8*)&sKT[wn + j*16 + fm][k0 + fk];
                    acc2[j] = mfma1(a, bv, acc2[j]);
                }
            }
            short* Sb = S + ((size_t)(bh*NC + c)) * CH * DP;
            #pragma unroll
            for (int j = 0; j < 5; ++j)
                #pragma unroll
                for (int rr = 0; rr < 4; ++rr) {
                    short* pcol = Sb + (size_t)(wm + crow0 + rr) * DP
                                     + wn + j*16 + (ccol & ~3);
                    st_quad(pcol, f2bf_rne(acc2[j][rr]), lane);
                }
        }
    }
    group_arrive(&bar[(16 + bh23) * 16]);              // c2[bh]: S/Z chunk done
    group_wait(&bar[(16 + bh23) * 16], 8u);            // need all 8 chunks of bh

    // ---------------- phase 3: chunk_out -------------------------------------
    {
        float (*sQP)[17]          = (float(*)[17])(smem);
        float (*sKP)[17]          = (float(*)[17])(smem + 4352);
        unsigned short (*sQf)[168]= (unsigned short(*)[168])(smem + 8704);
        unsigned short (*sKf)[168]= (unsigned short(*)[168])(smem + 30208);
        unsigned short (*sPb)[168]= (unsigned short(*)[168])(smem + 51712);
        unsigned short (*sAb)[72] = (unsigned short(*)[72])(smem + 73216);
        unsigned short (*sVT)[72] = (unsigned short(*)[72])(smem + 82432);
        float* sZp  = (float*)(smem + 91648);
        float* sDen = (float*)(smem + 92288);
        const int bh = bh23, c = c23;
        const int b = bh >> 4, h = bh & 15;
        const int wm = (w & 3) * 16, wn = (w >> 2) * 16;
        const int r = (tid & 255) >> 2, q4 = tid & 3;
        const size_t rowbase = (size_t)(b*T + c*CH + r) * 1536;
        f32x4 accA = {}, accI = {};
        if (tid < 256) {
            short4v qv = *(const short4v*)(Cp + rowbase + h*16 + q4*4);
            short4v kv = *(const short4v*)(Cp + rowbase + 256 + h*16 + q4*4);
            const short* pv = Cp + rowbase + 512 + h*HD + q4*16;
            bf16x8 v0 = *(const bf16x8*)pv, v1 = *(const bf16x8*)(pv + 8);
            float4 qf, kf;
            qf.x = bf2f((unsigned short)qv[0]); qf.y = bf2f((unsigned short)qv[1]);
            qf.z = bf2f((unsigned short)qv[2]); qf.w = bf2f((unsigned short)qv[3]);
            kf.x = bf2f((unsigned short)kv[0]); kf.y = bf2f((unsigned short)kv[1]);
            kf.z = bf2f((unsigned short)kv[2]); kf.w = bf2f((unsigned short)kv[3]);
            *(float4*)&sQP[r][q4*4] = qf;
            *(float4*)&sKP[r][q4*4] = kf;
            #pragma unroll
            for (int e = 0; e < 8; ++e) {
                sVT[q4*16 + e][r]     = (unsigned short)v0[e];
                sVT[q4*16 + 8 + e][r] = (unsigned short)v1[e];
            }
            if (tid < DP) {
                // Z-prefix: all 7 loads unconditional (c2[bh]==8 -> race-free),
                // value-masked accumulate.
                float zv[7];
                #pragma unroll
                for (int cc = 0; cc < 7; ++cc)
                    zv[cc] = Z[((size_t)(bh*NC + cc)) * DP + tid];
                float zz = 0.f;
                #pragma unroll
                for (int cc = 0; cc < 7; ++cc)
                    zz += (cc < c) ? zv[cc] : 0.f;
                sZp[tid] = zz;
            }
        }
        __syncthreads();
        {   // row-major features: sub = dst*8 + q4f*2 + gh
            const int r3 = tid >> 4, sub = tid & 15;
            const int dst = sub >> 3, q4f = (sub >> 1) & 3, gh = sub & 1;
            const float* x = dst ? sKP[r3] : sQP[r3];
            unsigned short* drow = dst ? sKf[r3] : sQf[r3];
            #pragma unroll
            for (int g = 0; g < 5; ++g) {
                const int gg = gh*5 + g;
                short4v s;
                #pragma unroll
                for (int e = 0; e < 4; ++e)
                    s[e] = (short)f2bf_rne(featval(x, q4f*40 + gg*4 + e));
                *(short4v*)(drow + q4f*40 + gg*4) = s;
            }
        }
        {   // S-prefix sums, 1024 threads, unconditional 7-load batches.
            for (int e = tid; e < 1280; e += 1024) {
                const int d = e / 20, D8 = (e % 20) * 8;
                bf16x8 raw[7];
                #pragma unroll
                for (int cc = 0; cc < 7; ++cc)
                    raw[cc] = *(const bf16x8*)(S + (((size_t)(bh*NC + cc)) * CH + d) * DP + D8);
                float a8[8] = {};
                #pragma unroll
                for (int cc = 0; cc < 7; ++cc) {
                    #pragma unroll
                    for (int e2 = 0; e2 < 8; ++e2)
                        a8[e2] += (cc < c) ? bf2f((unsigned short)raw[cc][e2]) : 0.f;
                }
                bf16x8 o;
                #pragma unroll
                for (int e2 = 0; e2 < 8; ++e2) o[e2] = (short)f2bf_rne(a8[e2]);
                *(bf16x8*)&sPb[d][D8] = o;
            }
        }
        __syncthreads();
        {   // MFMA stage 1: A = Qf.Kf^T, I = Qf.Pb^T
            for (int k0 = 0; k0 < DP; k0 += 32) {
                bf16x8 qv = *(const bf16x8*)&sQf[wm + fm][k0 + fk];
                bf16x8 kv = *(const bf16x8*)&sKf[wn + fm][k0 + fk];
                bf16x8 pv = *(const bf16x8*)&sPb[wn + fm][k0 + fk];
                accA = mfma1(qv, kv, accA);
                accI = mfma1(qv, pv, accI);
            }
        }
        if (tid < 256) {   // denominator dot with Z-prefix
            float dp = 0.f;
            #pragma unroll
            for (int g = 0; g < 5; ++g) {
                bf16x8 v = *(const bf16x8*)&sQf[r][q4*40 + g*8];
                #pragma unroll
                for (int e = 0; e < 8; ++e)
                    dp += bf2f((unsigned short)v[e]) * sZp[q4*40 + g*8 + e];
            }
            dp += __shfl_xor(dp, 1);
            dp += __shfl_xor(dp, 2);
            if (q4 == 0) sDen[r] = dp;
        }
        {   // causal-mask A into LDS (each wave its 16x16 tile)
            #pragma unroll
            for (int rr = 0; rr < 4; ++rr) {
                const int t_ = wm + crow0 + rr, s_ = wn + ccol;
                sAb[t_][s_] = (s_ <= t_) ? f2bf_rne(accA[rr]) : 0;
            }
        }
        __syncthreads();
        if (tid < 256) {   // row-sum of causal A into denominator
            float rs = 0.f;
            bf16x8 v0 = *(const bf16x8*)&sAb[r][q4*16];
            bf16x8 v1 = *(const bf16x8*)&sAb[r][q4*16 + 8];
            #pragma unroll
            for (int e = 0; e < 8; ++e)
                rs += bf2f((unsigned short)v0[e]) + bf2f((unsigned short)v1[e]);
            rs += __shfl_xor(rs, 1);
            rs += __shfl_xor(rs, 2);
            if (q4 == 0) sDen[r] += rs;
        }
        __syncthreads();
        {   // MFMA stage 2: I += Ab.VT^T ; write Y
            #pragma unroll
            for (int k0 = 0; k0 < 64; k0 += 32) {
                bf16x8 a = *(const bf16x8*)&sAb[wm + fm][k0 + fk];
                bf16x8 bv = *(const bf16x8*)&sVT[wn + fm][k0 + fk];
                accI = mfma1(a, bv, accI);
            }
            #pragma unroll
            for (int rr = 0; rr < 4; ++rr) {
                const int t_ = wm + crow0 + rr;
                const float inv = 1.f / (sDen[t_] + 1e-12f);
                const size_t grow = (size_t)(b*T + c*CH + t_) * 1024 + h*HD;
                short* pcol = Y + grow + wn + (ccol & ~3);
                st_quad(pcol, f2bf_rne(accI[rr] * inv), lane);
            }
        }
    }
    group_arrive(&bar[(48 + strp23) * 16]);            // c3[stripe]: Y rows done
    // phase-4 Wo prefetch (all 3 chunks): pure input, load BEFORE the wait.
    const int p4_half = tid >> 9;
    const int p4_ht = tid & 511;
    const int p4_bn = tn * 64;
    const int p4_srow = p4_ht >> 3, p4_skq = (p4_ht & 7) * 8;
    const float* p4_pB = Wo + (size_t)(p4_bn + p4_srow) * 1024 + p4_half * 512 + p4_skq;
    float4 w00 = *(const float4*)p4_pB,         w01 = *(const float4*)(p4_pB + 4);
    float4 wA0 = *(const float4*)(p4_pB + 64),  wA1 = *(const float4*)(p4_pB + 68);
    float4 wB0 = *(const float4*)(p4_pB + 128), wB1 = *(const float4*)(p4_pB + 132);
    group_wait(&bar[(48 + tm) * 16], 16u);             // need Y stripe tm

    // ---------------- phase 4: gemm_out  out = Y @ bf16(Wo)^T ----------------
    // 2-deep prefetch mirror of phase 1.
    {
        short (*sA)[2][64][72] = (short(*)[2][64][72])(smem);
        short (*sB)[2][64][72] = (short(*)[2][64][72])(smem + 36864);
        float (*sRed)[8]       = (float(*)[8])(smem + 73728);           // 16384
        const int half = p4_half;
        const int ht = p4_ht;
        const int wh = w & 7;
        const int bm = tm * 64, bn = p4_bn;
        const int wm = (wh & 3) * 16, wn = (wh >> 2) * 32;
        const int srow = p4_srow, skq = p4_skq;
        const int kbase = half * 512;
        f32x4 acc[2] = {};
        const short* pA = Y + (size_t)(bm + srow) * 1024 + kbase + skq;
        const float* pB = p4_pB;
        // issue all 3 Y chunk loads together (one exposed MALL latency)
        bf16x8 y0  = *(const bf16x8*)pA;
        bf16x8 yA  = *(const bf16x8*)(pA + 64);
        bf16x8 yB  = *(const bf16x8*)(pA + 128);
        float4 qbA0 = wA0, qbA1 = wA1;
        float4 qbB0 = wB0, qbB1 = wB1;
        *(bf16x8*)&sA[half][0][srow][skq] = y0;
        *(bf16x8*)&sB[half][0][srow][skq] = cvt8(w00, w01);
        __syncthreads();
        for (int k0 = 0; k0 < 512; k0 += 128) {
            // ---- sub0: consume buf0 (data[k0]); stage setA -> buf1
            {
                bf16x8 a[2], b2[2][2];
                #pragma unroll
                for (int ks = 0; ks < 2; ++ks) {
                    a[ks] = *(const bf16x8*)&sA[half][0][wm + fm][ks*32 + fk];
                    #pragma unroll
                    for (int j = 0; j < 2; ++j)
                        b2[ks][j] = *(const bf16x8*)&sB[half][0][wn + j*16 + fm][ks*32 + fk];
                }
                *(bf16x8*)&sA[half][1][srow][skq] = yA;
                *(bf16x8*)&sB[half][1][srow][skq] = cvt8(qbA0, qbA1);
                if (k0 + 192 < 512) {
                    yA = *(const bf16x8*)(pA + k0 + 192);
                    const float* pB2 = pB + k0 + 192;
                    qbA0 = *(const float4*)pB2; qbA1 = *(const float4*)(pB2 + 4);
                }
                #pragma unroll
                for (int ks = 0; ks < 2; ++ks)
                    #pragma unroll
                    for (int j = 0; j < 2; ++j)
                        acc[j] = mfma1(a[ks], b2[ks][j], acc[j]);
                __syncthreads();
            }
            // ---- sub1: consume buf1 (data[k0+64]); stage setB -> buf0
            {
                bf16x8 a[2], b2[2][2];
                #pragma unroll
                for (int ks = 0; ks < 2; ++ks) {
                    a[ks] = *(const bf16x8*)&sA[half][1][wm + fm][ks*32 + fk];
                    #pragma unroll
                    for (int j = 0; j < 2; ++j)
                        b2[ks][j] = *(const bf16x8*)&sB[half][1][wn + j*16 + fm][ks*32 + fk];
                }
                if (k0 + 128 < 512) {
                    *(bf16x8*)&sA[half][0][srow][skq] = yB;
                    *(bf16x8*)&sB[half][0][srow][skq] = cvt8(qbB0, qbB1);
                }
                if (k0 + 256 < 512) {
                    yB = *(const bf16x8*)(pA + k0 + 256);
                    const float* pB2 = pB + k0 + 256;
                    qbB0 = *(const float4*)pB2; qbB1 = *(const float4*)(pB2 + 4);
                }
                #pragma unroll
                for (int ks = 0; ks < 2; ++ks)
                    #pragma unroll
                    for (int j = 0; j < 2; ++j)
                        acc[j] = mfma1(a[ks], b2[ks][j], acc[j]);
                __syncthreads();
            }
        }
        __syncthreads();
        if (half == 1) {
            #pragma unroll
            for (int j = 0; j < 2; ++j)
                *(f32x4*)&sRed[ht][j * 4] = acc[j];
        }
        __syncthreads();
        if (half == 0) {
            #pragma unroll
            for (int j = 0; j < 2; ++j) {
                f32x4 p = *(const f32x4*)&sRed[ht][j * 4];
                #pragma unroll
                for (int r = 0; r < 4; ++r)
                    out[(size_t)(bm + wm + crow0 + r) * 1024 + bn + wn + j*16 + ccol] =
                        acc[j][r] + p[r];
            }
        }
    }
}

extern "C" void kernel_launch(void* const* d_in, const int* in_sizes, int n_in,
                              void* d_out, int out_size, void* d_ws, size_t ws_size,
                              hipStream_t stream) {
    const float* hs = (const float*)d_in[0];
    const float* Wq = (const float*)d_in[1];
    const float* Wk = (const float*)d_in[2];
    const float* Wv = (const float*)d_in[3];
    const float* Wo = (const float*)d_in[4];
    float* out = (float*)d_out;

    char* p = (char*)d_ws;
    short* Cp  = (short*)p; p += (size_t)1024*1536*2;
    short* S   = (short*)p; p += (size_t)32*NC*CH*DP*2;
    float* Z   = (float*)p; p += (size_t)32*NC*DP*4;
    short* Y   = (short*)p; p += (size_t)1048576*2;
    unsigned* bar = (unsigned*)p; p += 4096;

    wsflush<<<dim3(64), dim3(64), 0, stream>>>();
    barinit<<<dim3(1), dim3(64), 0, stream>>>(bar);
    fused<<<dim3(256), dim3(1024), 0, stream>>>(hs, Wq, Wk, Wv, Wo,
                                                Cp, S, Z, Y, out, bar);
}

// Round 13
// 110.845 us; speedup vs baseline: 1.0231x; 1.0131x over previous
//
#include <hip/hip_runtime.h>

#define T 512
#define B 2
#define NH 16
#define FD 16
#define HD 64
#define DP 160
#define CH 64
#define NC 8

typedef __attribute__((ext_vector_type(4))) short short4v;
typedef __attribute__((ext_vector_type(8))) short bf16x8;
typedef __attribute__((ext_vector_type(4))) float f32x4;
typedef unsigned long long u64;

__constant__ unsigned char c_iu[120] = {
0,0,0,0,0,0,0,0,0,0,0,0,0,0,0,
1,1,1,1,1,1,1,1,1,1,1,1,1,1,
2,2,2,2,2,2,2,2,2,2,2,2,2,
3,3,3,3,3,3,3,3,3,3,3,3,
4,4,4,4,4,4,4,4,4,4,4,
5,5,5,5,5,5,5,5,5,5,
6,6,6,6,6,6,6,6,6,
7,7,7,7,7,7,7,7,
8,8,8,8,8,8,8,
9,9,9,9,9,9,
10,10,10,10,10,
11,11,11,11,
12,12,12,
13,13,
14};
__constant__ unsigned char c_ju[120] = {
1,2,3,4,5,6,7,8,9,10,11,12,13,14,15,
2,3,4,5,6,7,8,9,10,11,12,13,14,15,
3,4,5,6,7,8,9,10,11,12,13,14,15,
4,5,6,7,8,9,10,11,12,13,14,15,
5,6,7,8,9,10,11,12,13,14,15,
6,7,8,9,10,11,12,13,14,15,
7,8,9,10,11,12,13,14,15,
8,9,10,11,12,13,14,15,
9,10,11,12,13,14,15,
10,11,12,13,14,15,
11,12,13,14,15,
12,13,14,15,
13,14,15,
14,15,
15};

__device__ inline unsigned short f2bf_rne(float x) {
    unsigned u = __float_as_uint(x);
    u += 0x7fff + ((u >> 16) & 1);
    return (unsigned short)(u >> 16);
}
__device__ inline float bf2f(unsigned short h) {
    return __uint_as_float(((unsigned)h) << 16);
}
__device__ inline f32x4 mfma1(bf16x8 a, bf16x8 b, f32x4 acc) {
    return __builtin_amdgcn_mfma_f32_16x16x32_bf16(a, b, acc, 0, 0, 0);
}
__device__ inline bf16x8 cvt8(float4 a, float4 b) {
    bf16x8 r;
    r[0]=(short)f2bf_rne(a.x); r[1]=(short)f2bf_rne(a.y);
    r[2]=(short)f2bf_rne(a.z); r[3]=(short)f2bf_rne(a.w);
    r[4]=(short)f2bf_rne(b.x); r[5]=(short)f2bf_rne(b.y);
    r[6]=(short)f2bf_rne(b.z); r[7]=(short)f2bf_rne(b.w);
    return r;
}
// Taylor feature value for index D from x[16] (exact same formula/rounding).
__device__ inline float featval(const float* __restrict__ x, int D) {
    if (D == 0)       return 1.f;
    else if (D < 17)  return x[D-1] * 0.5f;
    else if (D < 33)  { float a = x[D-17]; return a * a * 0.17677669529663687f; }
    else if (D < 153) { int p = D - 33; return x[c_iu[p]] * x[c_ju[p]] * 0.25f; }
    return 0.f;
}

// ---- Coherent WRITE path (sc1 / MALL write-through). Reads cached (R6-R12).
__device__ inline void st_coh_u32(unsigned* p, unsigned v) {
    __hip_atomic_store(p, v, __ATOMIC_RELAXED, __HIP_MEMORY_SCOPE_AGENT);
}
__device__ inline unsigned ld_coh_u32(const unsigned* p) {
    return __hip_atomic_load((unsigned*)p, __ATOMIC_RELAXED, __HIP_MEMORY_SCOPE_AGENT);
}
// Quad-pack store: 4 consecutive lanes fold bf16 cols into one u64 store.
__device__ inline void st_quad(short* pbase, unsigned short v, int lane) {
    unsigned x = v;
    unsigned o1 = (unsigned)__shfl_xor((int)x, 1);
    unsigned lo = ((lane & 1) == 0) ? (x | (o1 << 16)) : (o1 | (x << 16));
    unsigned o2 = (unsigned)__shfl_xor((int)lo, 2);
    if ((lane & 3) == 0) {
        u64 q = (u64)lo | ((u64)o2 << 32);
        __hip_atomic_store((u64*)pbase, q, __ATOMIC_RELAXED, __HIP_MEMORY_SCOPE_AGENT);
    }
}

// ---- Producer-group sync (R10-proven): no cache maintenance anywhere.
__device__ inline void group_arrive(unsigned* cnt) {
    __builtin_amdgcn_s_waitcnt(0);     // all prior sc1 stores reached MALL
    __syncthreads();                   // every wave of the block drained
    if (threadIdx.x == 0)
        __hip_atomic_fetch_add(cnt, 1u, __ATOMIC_RELAXED, __HIP_MEMORY_SCOPE_AGENT);
}
__device__ inline void group_wait(const unsigned* cnt, unsigned tgt) {
    if (threadIdx.x == 0) {
        for (unsigned it = 0; it < (1u << 17); ++it) {   // bounded: no hang
            if (ld_coh_u32(cnt) >= tgt) break;
            __builtin_amdgcn_s_sleep(2);
        }
    }
    __syncthreads();
}

// Merged init (R13): every block writebacks+invalidates its XCD L2 (harness
// poison-fill residue); block 0 additionally zeroes the 64 counter slots.
// One kernel instead of two -> one fewer dispatch boundary in the graph.
__global__ void initk(unsigned* __restrict__ bar) {
    if (threadIdx.x == 0) __builtin_amdgcn_fence(__ATOMIC_SEQ_CST, "agent");
    __syncthreads();
    if (blockIdx.x == 0) st_coh_u32(&bar[threadIdx.x * 16], 0u);
}

// ============================================================================
// FUSED persistent kernel (R12 body + R13 LDS carry-over):
// 256 blocks x 1024 threads, group-counter sync, XCD-rectangle swizzle,
// 2-deep GEMM prefetch. R13 delta: sKP (K-proj rows, f32) and sVT (V
// transposed) are pinned at fixed LDS offsets in phases 2 AND 3 -> phase 3
// skips the K/V global reloads and the V re-transpose (bit-identical values,
// same bytes & conversions).
// ============================================================================
__global__ __launch_bounds__(1024)
void fused(const float* __restrict__ hs, const float* __restrict__ Wq,
           const float* __restrict__ Wk, const float* __restrict__ Wv,
           const float* __restrict__ Wo,
           short* __restrict__ Cp, short* __restrict__ S, float* __restrict__ Z,
           short* __restrict__ Y, float* __restrict__ out,
           unsigned* __restrict__ bar) {
    __shared__ __align__(16) char smem[116736];
    const int tid = threadIdx.x;
    const int bid = blockIdx.x;
    const int lane = tid & 63;
    const int w = tid >> 6;                  // wave 0..15
    const int fm = lane & 15, fk = (lane >> 4) * 8;
    const int crow0 = (lane >> 4) * 4, ccol = lane & 15;

    // XCD-rectangle remap for GEMM phases: XCD g owns 8bm x 4bn tiles.
    const int g1 = bid & 7, i1 = bid >> 3;
    const int tm = ((g1 & 1) << 3) + (i1 & 7);         // bm tile 0..15
    const int tn = ((g1 >> 1) << 2) + (i1 >> 3);       // bn tile 0..15

    // phase-2/3 identity and its producer stripe
    const int bh23 = bid & 31, c23 = bid >> 5;
    const int strp23 = ((bh23 >> 4) << 3) + c23;       // b*8 + c

    // Shared phase-2/3 overlays (FIXED offsets, carried across the c2 sync):
    float (*sKP)[17]          = (float(*)[17])(smem);                    // 0..4352
    unsigned short (*sVT)[72] = (unsigned short(*)[72])(smem + 4352);    // ..13568

    // ---------------- phase 1: gemm_proj  Cp = bf16(hs) @ bf16(W)^T ----------
    {
        short (*sA)[2][64][72] = (short(*)[2][64][72])(smem);            // 36864
        short (*sB)[2][96][72] = (short(*)[2][96][72])(smem + 36864);    // 55296
        float (*sRed)[12]      = (float(*)[12])(smem + 92160);          // 24576
        const int half = tid >> 9;
        const int ht = tid & 511;
        const int wh = w & 7;
        const int bm = tm * 64, bn = tn * 96;
        const int wm = (wh & 3) * 16, wn = (wh >> 2) * 48;
        const int srA = ht >> 3, skA = (ht & 7) * 8;       // 8 shorts/thread
        const int srB = ht >> 2, skB = (ht & 3) * 16;      // 16 shorts/thread
        const int kbase = half * 512;
        f32x4 acc[3] = {};
        const float* pA = hs + (size_t)(bm + srA) * 1024 + kbase + skA;
        const int Rb = bn + (ht < 384 ? srB : 0);
        const float* wsrc = (Rb < 256) ? (Wq + (size_t)Rb * 1024)
                          : (Rb < 512) ? (Wk + (size_t)(Rb - 256) * 1024)
                                       : (Wv + (size_t)(Rb - 512) * 1024);
        const float* pB = wsrc + kbase + skB;
        // --- stage 0 direct to LDS
        {
            float4 t0 = *(const float4*)pA, t1 = *(const float4*)(pA + 4);
            float4 u0, u1, u2, u3;
            if (ht < 384) {
                u0 = *(const float4*)pB;        u1 = *(const float4*)(pB + 4);
                u2 = *(const float4*)(pB + 8);  u3 = *(const float4*)(pB + 12);
            }
            *(bf16x8*)&sA[half][0][srA][skA] = cvt8(t0, t1);
            if (ht < 384) {
                *(bf16x8*)&sB[half][0][srB][skB]     = cvt8(u0, u1);
                *(bf16x8*)&sB[half][0][srB][skB + 8] = cvt8(u2, u3);
            }
        }
        // --- prefetch set A (data[64]) and set B (data[128])
        float4 aA0, aA1, bA0, bA1, bA2, bA3;
        float4 aB0, aB1, bB0, bB1, bB2, bB3;
        aA0 = *(const float4*)(pA + 64);  aA1 = *(const float4*)(pA + 68);
        aB0 = *(const float4*)(pA + 128); aB1 = *(const float4*)(pA + 132);
        if (ht < 384) {
            bA0 = *(const float4*)(pB + 64);  bA1 = *(const float4*)(pB + 68);
            bA2 = *(const float4*)(pB + 72);  bA3 = *(const float4*)(pB + 76);
            bB0 = *(const float4*)(pB + 128); bB1 = *(const float4*)(pB + 132);
            bB2 = *(const float4*)(pB + 136); bB3 = *(const float4*)(pB + 140);
        }
        __syncthreads();
        for (int k0 = 0; k0 < 512; k0 += 128) {
            // ---- sub0: consume LDS buf0 (data[k0]); stage setA -> buf1
            {
                bf16x8 a[2], bfr[2][3];
                #pragma unroll
                for (int ks = 0; ks < 2; ++ks) {
                    a[ks] = *(const bf16x8*)&sA[half][0][wm + fm][ks*32 + fk];
                    #pragma unroll
                    for (int j = 0; j < 3; ++j)
                        bfr[ks][j] = *(const bf16x8*)&sB[half][0][wn + j*16 + fm][ks*32 + fk];
                }
                *(bf16x8*)&sA[half][1][srA][skA] = cvt8(aA0, aA1);
                if (ht < 384) {
                    *(bf16x8*)&sB[half][1][srB][skB]     = cvt8(bA0, bA1);
                    *(bf16x8*)&sB[half][1][srB][skB + 8] = cvt8(bA2, bA3);
                }
                if (k0 + 192 < 512) {
                    const float* pA2 = pA + k0 + 192;
                    aA0 = *(const float4*)pA2; aA1 = *(const float4*)(pA2 + 4);
                    if (ht < 384) {
                        const float* pB2 = pB + k0 + 192;
                        bA0 = *(const float4*)pB2;       bA1 = *(const float4*)(pB2 + 4);
                        bA2 = *(const float4*)(pB2 + 8); bA3 = *(const float4*)(pB2 + 12);
                    }
                }
                #pragma unroll
                for (int ks = 0; ks < 2; ++ks)
                    #pragma unroll
                    for (int j = 0; j < 3; ++j)
                        acc[j] = mfma1(a[ks], bfr[ks][j], acc[j]);
                __syncthreads();
            }
            // ---- sub1: consume LDS buf1 (data[k0+64]); stage setB -> buf0
            {
                bf16x8 a[2], bfr[2][3];
                #pragma unroll
                for (int ks = 0; ks < 2; ++ks) {
                    a[ks] = *(const bf16x8*)&sA[half][1][wm + fm][ks*32 + fk];
                    #pragma unroll
                    for (int j = 0; j < 3; ++j)
                        bfr[ks][j] = *(const bf16x8*)&sB[half][1][wn + j*16 + fm][ks*32 + fk];
                }
                if (k0 + 128 < 512) {
                    *(bf16x8*)&sA[half][0][srA][skA] = cvt8(aB0, aB1);
                    if (ht < 384) {
                        *(bf16x8*)&sB[half][0][srB][skB]     = cvt8(bB0, bB1);
                        *(bf16x8*)&sB[half][0][srB][skB + 8] = cvt8(bB2, bB3);
                    }
                }
                if (k0 + 256 < 512) {
                    const float* pA2 = pA + k0 + 256;
                    aB0 = *(const float4*)pA2; aB1 = *(const float4*)(pA2 + 4);
                    if (ht < 384) {
                        const float* pB2 = pB + k0 + 256;
                        bB0 = *(const float4*)pB2;       bB1 = *(const float4*)(pB2 + 4);
                        bB2 = *(const float4*)(pB2 + 8); bB3 = *(const float4*)(pB2 + 12);
                    }
                }
                #pragma unroll
                for (int ks = 0; ks < 2; ++ks)
                    #pragma unroll
                    for (int j = 0; j < 3; ++j)
                        acc[j] = mfma1(a[ks], bfr[ks][j], acc[j]);
                __syncthreads();
            }
        }
        __syncthreads();
        if (half == 1) {
            #pragma unroll
            for (int j = 0; j < 3; ++j)
                *(f32x4*)&sRed[ht][j * 4] = acc[j];
        }
        __syncthreads();
        if (half == 0) {
            #pragma unroll
            for (int j = 0; j < 3; ++j) {
                f32x4 o = acc[j];
                f32x4 p = *(const f32x4*)&sRed[ht][j * 4];
                #pragma unroll
                for (int r = 0; r < 4; ++r) {
                    short* pcol = Cp + (size_t)(bm + wm + crow0 + r) * 1536
                                     + bn + wn + j*16 + (ccol & ~3);
                    st_quad(pcol, f2bf_rne(o[r] + p[r]), lane);
                }
            }
        }
    }
    group_arrive(&bar[tm * 16]);                       // c1[bm]: stripe done
    group_wait(&bar[strp23 * 16], 16u);                // need Cp stripe b*8+c

    // ---------------- phase 2: chunk_state -----------------------------------
    // sKP (0) and sVT (4352) persist into phase 3. sKT lives at 13568.
    {
        unsigned short (*sKT)[72] = (unsigned short(*)[72])(smem + 13568);
        const int bh = bh23, c = c23;
        const int b = bh >> 4, h = bh & 15;
        const int wm = (w & 3) * 16, wn = (w >> 2) * 80;   // valid for w<8
        const int r = (tid & 255) >> 2, q4 = tid & 3;
        const size_t rowbase = (size_t)(b*T + c*CH + r) * 1536;
        if (tid < 256) {
            short4v kv = *(const short4v*)(Cp + rowbase + 256 + h*16 + q4*4);
            const short* pv = Cp + rowbase + 512 + h*HD + q4*16;
            bf16x8 v0 = *(const bf16x8*)pv, v1 = *(const bf16x8*)(pv + 8);
            float4 kf;
            kf.x = bf2f((unsigned short)kv[0]); kf.y = bf2f((unsigned short)kv[1]);
            kf.z = bf2f((unsigned short)kv[2]); kf.w = bf2f((unsigned short)kv[3]);
            *(float4*)&sKP[r][q4*4] = kf;
            #pragma unroll
            for (int e = 0; e < 8; ++e) {
                sVT[q4*16 + e][r]     = (unsigned short)v0[e];
                sVT[q4*16 + 8 + e][r] = (unsigned short)v1[e];
            }
        }
        __syncthreads();
        {   // transposed features, 4x parallel
            const int r3 = tid >> 4, sub = tid & 15;
            const int q4t = sub & 3, gh = sub >> 2;
            const float* x = sKP[r3];
            #pragma unroll
            for (int dd = 0; dd < 10; ++dd) {
                const int D = q4t*40 + gh*10 + dd;
                sKT[D][r3] = f2bf_rne(featval(x, D));
            }
        }
        __syncthreads();
        if (tid < DP) {
            float zz = 0.f;
            #pragma unroll
            for (int blk = 0; blk < 8; ++blk) {
                bf16x8 v = *(const bf16x8*)&sKT[tid][blk*8];
                #pragma unroll
                for (int e = 0; e < 8; ++e) zz += bf2f((unsigned short)v[e]);
            }
            st_coh_u32((unsigned*)(Z + ((size_t)(bh*NC + c)) * DP + tid),
                       __float_as_uint(zz));
        }
        if (w < 8) {
            f32x4 acc2[5] = {};
            #pragma unroll
            for (int k0 = 0; k0 < 64; k0 += 32) {
                bf16x8 a = *(const bf16x8*)&sVT[wm + fm][k0 + fk];
                #pragma unroll
                for (int j = 0; j < 5; ++j) {
                    bf16x8 bv = *(const bf16x8*)&sKT[wn + j*16 + fm][k0 + fk];
                    acc2[j] = mfma1(a, bv, acc2[j]);
                }
            }
            short* Sb = S + ((size_t)(bh*NC + c)) * CH * DP;
            #pragma unroll
            for (int j = 0; j < 5; ++j)
                #pragma unroll
                for (int rr = 0; rr < 4; ++rr) {
                    short* pcol = Sb + (size_t)(wm + crow0 + rr) * DP
                                     + wn + j*16 + (ccol & ~3);
                    st_quad(pcol, f2bf_rne(acc2[j][rr]), lane);
                }
        }
    }
    group_arrive(&bar[(16 + bh23) * 16]);              // c2[bh]: S/Z chunk done
    group_wait(&bar[(16 + bh23) * 16], 8u);            // need all 8 chunks of bh

    // ---------------- phase 3: chunk_out (reuses sKP & sVT from phase 2) -----
    {
        float (*sQP)[17]          = (float(*)[17])(smem + 13568);            // 4352
        unsigned short (*sQf)[168]= (unsigned short(*)[168])(smem + 17920);  // 21504
        unsigned short (*sKf)[168]= (unsigned short(*)[168])(smem + 39424);  // 21504
        unsigned short (*sPb)[168]= (unsigned short(*)[168])(smem + 60928);  // 21504
        unsigned short (*sAb)[72] = (unsigned short(*)[72])(smem + 82432);   // 9216
        float* sZp  = (float*)(smem + 91648);
        float* sDen = (float*)(smem + 92288);
        const int bh = bh23, c = c23;
        const int b = bh >> 4, h = bh & 15;
        const int wm = (w & 3) * 16, wn = (w >> 2) * 16;
        const int r = (tid & 255) >> 2, q4 = tid & 3;
        const size_t rowbase = (size_t)(b*T + c*CH + r) * 1536;
        f32x4 accA = {}, accI = {};
        if (tid < 256) {
            short4v qv = *(const short4v*)(Cp + rowbase + h*16 + q4*4);
            float4 qf;
            qf.x = bf2f((unsigned short)qv[0]); qf.y = bf2f((unsigned short)qv[1]);
            qf.z = bf2f((unsigned short)qv[2]); qf.w = bf2f((unsigned short)qv[3]);
            *(float4*)&sQP[r][q4*4] = qf;
            if (tid < DP) {
                // Z-prefix: all 7 loads unconditional (c2[bh]==8 -> race-free),
                // value-masked accumulate.
                float zv[7];
                #pragma unroll
                for (int cc = 0; cc < 7; ++cc)
                    zv[cc] = Z[((size_t)(bh*NC + cc)) * DP + tid];
                float zz = 0.f;
                #pragma unroll
                for (int cc = 0; cc < 7; ++cc)
                    zz += (cc < c) ? zv[cc] : 0.f;
                sZp[tid] = zz;
            }
        }
        __syncthreads();
        {   // row-major features: sub = dst*8 + q4f*2 + gh (sKP carried over)
            const int r3 = tid >> 4, sub = tid & 15;
            const int dst = sub >> 3, q4f = (sub >> 1) & 3, gh = sub & 1;
            const float* x = dst ? sKP[r3] : sQP[r3];
            unsigned short* drow = dst ? sKf[r3] : sQf[r3];
            #pragma unroll
            for (int g = 0; g < 5; ++g) {
                const int gg = gh*5 + g;
                short4v s;
                #pragma unroll
                for (int e = 0; e < 4; ++e)
                    s[e] = (short)f2bf_rne(featval(x, q4f*40 + gg*4 + e));
                *(short4v*)(drow + q4f*40 + gg*4) = s;
            }
        }
        {   // S-prefix sums, 1024 threads, unconditional 7-load batches.
            for (int e = tid; e < 1280; e += 1024) {
                const int d = e / 20, D8 = (e % 20) * 8;
                bf16x8 raw[7];
                #pragma unroll
                for (int cc = 0; cc < 7; ++cc)
                    raw[cc] = *(const bf16x8*)(S + (((size_t)(bh*NC + cc)) * CH + d) * DP + D8);
                float a8[8] = {};
                #pragma unroll
                for (int cc = 0; cc < 7; ++cc) {
                    #pragma unroll
                    for (int e2 = 0; e2 < 8; ++e2)
                        a8[e2] += (cc < c) ? bf2f((unsigned short)raw[cc][e2]) : 0.f;
                }
                bf16x8 o;
                #pragma unroll
                for (int e2 = 0; e2 < 8; ++e2) o[e2] = (short)f2bf_rne(a8[e2]);
                *(bf16x8*)&sPb[d][D8] = o;
            }
        }
        __syncthreads();
        {   // MFMA stage 1: A = Qf.Kf^T, I = Qf.Pb^T
            for (int k0 = 0; k0 < DP; k0 += 32) {
                bf16x8 qv = *(const bf16x8*)&sQf[wm + fm][k0 + fk];
                bf16x8 kv = *(const bf16x8*)&sKf[wn + fm][k0 + fk];
                bf16x8 pv = *(const bf16x8*)&sPb[wn + fm][k0 + fk];
                accA = mfma1(qv, kv, accA);
                accI = mfma1(qv, pv, accI);
            }
        }
        if (tid < 256) {   // denominator dot with Z-prefix
            float dp = 0.f;
            #pragma unroll
            for (int g = 0; g < 5; ++g) {
                bf16x8 v = *(const bf16x8*)&sQf[r][q4*40 + g*8];
                #pragma unroll
                for (int e = 0; e < 8; ++e)
                    dp += bf2f((unsigned short)v[e]) * sZp[q4*40 + g*8 + e];
            }
            dp += __shfl_xor(dp, 1);
            dp += __shfl_xor(dp, 2);
            if (q4 == 0) sDen[r] = dp;
        }
        {   // causal-mask A into LDS (each wave its 16x16 tile)
            #pragma unroll
            for (int rr = 0; rr < 4; ++rr) {
                const int t_ = wm + crow0 + rr, s_ = wn + ccol;
                sAb[t_][s_] = (s_ <= t_) ? f2bf_rne(accA[rr]) : 0;
            }
        }
        __syncthreads();
        if (tid < 256) {   // row-sum of causal A into denominator
            float rs = 0.f;
            bf16x8 v0 = *(const bf16x8*)&sAb[r][q4*16];
            bf16x8 v1 = *(const bf16x8*)&sAb[r][q4*16 + 8];
            #pragma unroll
            for (int e = 0; e < 8; ++e)
                rs += bf2f((unsigned short)v0[e]) + bf2f((unsigned short)v1[e]);
            rs += __shfl_xor(rs, 1);
            rs += __shfl_xor(rs, 2);
            if (q4 == 0) sDen[r] += rs;
        }
        __syncthreads();
        {   // MFMA stage 2: I += Ab.VT^T (sVT carried over) ; write Y
            #pragma unroll
            for (int k0 = 0; k0 < 64; k0 += 32) {
                bf16x8 a = *(const bf16x8*)&sAb[wm + fm][k0 + fk];
                bf16x8 bv = *(const bf16x8*)&sVT[wn + fm][k0 + fk];
                accI = mfma1(a, bv, accI);
            }
            #pragma unroll
            for (int rr = 0; rr < 4; ++rr) {
                const int t_ = wm + crow0 + rr;
                const float inv = 1.f / (sDen[t_] + 1e-12f);
                const size_t grow = (size_t)(b*T + c*CH + t_) * 1024 + h*HD;
                short* pcol = Y + grow + wn + (ccol & ~3);
                st_quad(pcol, f2bf_rne(accI[rr] * inv), lane);
            }
        }
    }
    group_arrive(&bar[(48 + strp23) * 16]);            // c3[stripe]: Y rows done
    // phase-4 Wo prefetch (all 3 chunks): pure input, load BEFORE the wait.
    const int p4_half = tid >> 9;
    const int p4_ht = tid & 511;
    const int p4_bn = tn * 64;
    const int p4_srow = p4_ht >> 3, p4_skq = (p4_ht & 7) * 8;
    const float* p4_pB = Wo + (size_t)(p4_bn + p4_srow) * 1024 + p4_half * 512 + p4_skq;
    float4 w00 = *(const float4*)p4_pB,         w01 = *(const float4*)(p4_pB + 4);
    float4 wA0 = *(const float4*)(p4_pB + 64),  wA1 = *(const float4*)(p4_pB + 68);
    float4 wB0 = *(const float4*)(p4_pB + 128), wB1 = *(const float4*)(p4_pB + 132);
    group_wait(&bar[(48 + tm) * 16], 16u);             // need Y stripe tm

    // ---------------- phase 4: gemm_out  out = Y @ bf16(Wo)^T ----------------
    // 2-deep prefetch mirror of phase 1.
    {
        short (*sA)[2][64][72] = (short(*)[2][64][72])(smem);
        short (*sB)[2][64][72] = (short(*)[2][64][72])(smem + 36864);
        float (*sRed)[8]       = (float(*)[8])(smem + 73728);           // 16384
        const int half = p4_half;
        const int ht = p4_ht;
        const int wh = w & 7;
        const int bm = tm * 64, bn = p4_bn;
        const int wm = (wh & 3) * 16, wn = (wh >> 2) * 32;
        const int srow = p4_srow, skq = p4_skq;
        const int kbase = half * 512;
        f32x4 acc[2] = {};
        const short* pA = Y + (size_t)(bm + srow) * 1024 + kbase + skq;
        const float* pB = p4_pB;
        // issue all 3 Y chunk loads together (one exposed MALL latency)
        bf16x8 y0  = *(const bf16x8*)pA;
        bf16x8 yA  = *(const bf16x8*)(pA + 64);
        bf16x8 yB  = *(const bf16x8*)(pA + 128);
        float4 qbA0 = wA0, qbA1 = wA1;
        float4 qbB0 = wB0, qbB1 = wB1;
        *(bf16x8*)&sA[half][0][srow][skq] = y0;
        *(bf16x8*)&sB[half][0][srow][skq] = cvt8(w00, w01);
        __syncthreads();
        for (int k0 = 0; k0 < 512; k0 += 128) {
            // ---- sub0: consume buf0 (data[k0]); stage setA -> buf1
            {
                bf16x8 a[2], b2[2][2];
                #pragma unroll
                for (int ks = 0; ks < 2; ++ks) {
                    a[ks] = *(const bf16x8*)&sA[half][0][wm + fm][ks*32 + fk];
                    #pragma unroll
                    for (int j = 0; j < 2; ++j)
                        b2[ks][j] = *(const bf16x8*)&sB[half][0][wn + j*16 + fm][ks*32 + fk];
                }
                *(bf16x8*)&sA[half][1][srow][skq] = yA;
                *(bf16x8*)&sB[half][1][srow][skq] = cvt8(qbA0, qbA1);
                if (k0 + 192 < 512) {
                    yA = *(const bf16x8*)(pA + k0 + 192);
                    const float* pB2 = pB + k0 + 192;
                    qbA0 = *(const float4*)pB2; qbA1 = *(const float4*)(pB2 + 4);
                }
                #pragma unroll
                for (int ks = 0; ks < 2; ++ks)
                    #pragma unroll
                    for (int j = 0; j < 2; ++j)
                        acc[j] = mfma1(a[ks], b2[ks][j], acc[j]);
                __syncthreads();
            }
            // ---- sub1: consume buf1 (data[k0+64]); stage setB -> buf0
            {
                bf16x8 a[2], b2[2][2];
                #pragma unroll
                for (int ks = 0; ks < 2; ++ks) {
                    a[ks] = *(const bf16x8*)&sA[half][1][wm + fm][ks*32 + fk];
                    #pragma unroll
                    for (int j = 0; j < 2; ++j)
                        b2[ks][j] = *(const bf16x8*)&sB[half][1][wn + j*16 + fm][ks*32 + fk];
                }
                if (k0 + 128 < 512) {
                    *(bf16x8*)&sA[half][0][srow][skq] = yB;
                    *(bf16x8*)&sB[half][0][srow][skq] = cvt8(qbB0, qbB1);
                }
                if (k0 + 256 < 512) {
                    yB = *(const bf16x8*)(pA + k0 + 256);
                    const float* pB2 = pB + k0 + 256;
                    qbB0 = *(const float4*)pB2; qbB1 = *(const float4*)(pB2 + 4);
                }
                #pragma unroll
                for (int ks = 0; ks < 2; ++ks)
                    #pragma unroll
                    for (int j = 0; j < 2; ++j)
                        acc[j] = mfma1(a[ks], b2[ks][j], acc[j]);
                __syncthreads();
            }
        }
        __syncthreads();
        if (half == 1) {
            #pragma unroll
            for (int j = 0; j < 2; ++j)
                *(f32x4*)&sRed[ht][j * 4] = acc[j];
        }
        __syncthreads();
        if (half == 0) {
            #pragma unroll
            for (int j = 0; j < 2; ++j) {
                f32x4 p = *(const f32x4*)&sRed[ht][j * 4];
                #pragma unroll
                for (int r = 0; r < 4; ++r)
                    out[(size_t)(bm + wm + crow0 + r) * 1024 + bn + wn + j*16 + ccol] =
                        acc[j][r] + p[r];
            }
        }
    }
}

extern "C" void kernel_launch(void* const* d_in, const int* in_sizes, int n_in,
                              void* d_out, int out_size, void* d_ws, size_t ws_size,
                              hipStream_t stream) {
    const float* hs = (const float*)d_in[0];
    const float* Wq = (const float*)d_in[1];
    const float* Wk = (const float*)d_in[2];
    const float* Wv = (const float*)d_in[3];
    const float* Wo = (const float*)d_in[4];
    float* out = (float*)d_out;

    char* p = (char*)d_ws;
    short* Cp  = (short*)p; p += (size_t)1024*1536*2;
    short* S   = (short*)p; p += (size_t)32*NC*CH*DP*2;
    float* Z   = (float*)p; p += (size_t)32*NC*DP*4;
    short* Y   = (short*)p; p += (size_t)1048576*2;
    unsigned* bar = (unsigned*)p; p += 4096;

    initk<<<dim3(64), dim3(64), 0, stream>>>(bar);
    fused<<<dim3(256), dim3(1024), 0, stream>>>(hs, Wq, Wk, Wv, Wo,
                                                Cp, S, Z, Y, out, bar);
}

// Round 14
// 109.919 us; speedup vs baseline: 1.0317x; 1.0084x over previous
//
#include <hip/hip_runtime.h>

#define T 512
#define B 2
#define NH 16
#define FD 16
#define HD 64
#define DP 160
#define CH 64
#define NC 8

typedef __attribute__((ext_vector_type(4))) short short4v;
typedef __attribute__((ext_vector_type(8))) short bf16x8;
typedef __attribute__((ext_vector_type(4))) float f32x4;
typedef unsigned long long u64;

__constant__ unsigned char c_iu[120] = {
0,0,0,0,0,0,0,0,0,0,0,0,0,0,0,
1,1,1,1,1,1,1,1,1,1,1,1,1,1,
2,2,2,2,2,2,2,2,2,2,2,2,2,
3,3,3,3,3,3,3,3,3,3,3,3,
4,4,4,4,4,4,4,4,4,4,4,
5,5,5,5,5,5,5,5,5,5,
6,6,6,6,6,6,6,6,6,
7,7,7,7,7,7,7,7,
8,8,8,8,8,8,8,
9,9,9,9,9,9,
10,10,10,10,10,
11,11,11,11,
12,12,12,
13,13,
14};
__constant__ unsigned char c_ju[120] = {
1,2,3,4,5,6,7,8,9,10,11,12,13,14,15,
2,3,4,5,6,7,8,9,10,11,12,13,14,15,
3,4,5,6,7,8,9,10,11,12,13,14,15,
4,5,6,7,8,9,10,11,12,13,14,15,
5,6,7,8,9,10,11,12,13,14,15,
6,7,8,9,10,11,12,13,14,15,
7,8,9,10,11,12,13,14,15,
8,9,10,11,12,13,14,15,
9,10,11,12,13,14,15,
10,11,12,13,14,15,
11,12,13,14,15,
12,13,14,15,
13,14,15,
14,15,
15};

__device__ inline unsigned short f2bf_rne(float x) {
    unsigned u = __float_as_uint(x);
    u += 0x7fff + ((u >> 16) & 1);
    return (unsigned short)(u >> 16);
}
__device__ inline float bf2f(unsigned short h) {
    return __uint_as_float(((unsigned)h) << 16);
}
__device__ inline f32x4 mfma1(bf16x8 a, bf16x8 b, f32x4 acc) {
    return __builtin_amdgcn_mfma_f32_16x16x32_bf16(a, b, acc, 0, 0, 0);
}
__device__ inline bf16x8 cvt8(float4 a, float4 b) {
    bf16x8 r;
    r[0]=(short)f2bf_rne(a.x); r[1]=(short)f2bf_rne(a.y);
    r[2]=(short)f2bf_rne(a.z); r[3]=(short)f2bf_rne(a.w);
    r[4]=(short)f2bf_rne(b.x); r[5]=(short)f2bf_rne(b.y);
    r[6]=(short)f2bf_rne(b.z); r[7]=(short)f2bf_rne(b.w);
    return r;
}
// Taylor feature value for index D from x[16] (exact same formula/rounding).
__device__ inline float featval(const float* __restrict__ x, int D) {
    if (D == 0)       return 1.f;
    else if (D < 17)  return x[D-1] * 0.5f;
    else if (D < 33)  { float a = x[D-17]; return a * a * 0.17677669529663687f; }
    else if (D < 153) { int p = D - 33; return x[c_iu[p]] * x[c_ju[p]] * 0.25f; }
    return 0.f;
}

// ---- Coherent WRITE path (sc1 / MALL write-through). Reads cached (R6-R13).
__device__ inline void st_coh_u32(unsigned* p, unsigned v) {
    __hip_atomic_store(p, v, __ATOMIC_RELAXED, __HIP_MEMORY_SCOPE_AGENT);
}
__device__ inline unsigned ld_coh_u32(const unsigned* p) {
    return __hip_atomic_load((unsigned*)p, __ATOMIC_RELAXED, __HIP_MEMORY_SCOPE_AGENT);
}
// Quad-pack store: 4 consecutive lanes fold bf16 cols into one u64 store.
__device__ inline void st_quad(short* pbase, unsigned short v, int lane) {
    unsigned x = v;
    unsigned o1 = (unsigned)__shfl_xor((int)x, 1);
    unsigned lo = ((lane & 1) == 0) ? (x | (o1 << 16)) : (o1 | (x << 16));
    unsigned o2 = (unsigned)__shfl_xor((int)lo, 2);
    if ((lane & 3) == 0) {
        u64 q = (u64)lo | ((u64)o2 << 32);
        __hip_atomic_store((u64*)pbase, q, __ATOMIC_RELAXED, __HIP_MEMORY_SCOPE_AGENT);
    }
}

// ---- Producer-group sync (R10-proven): no cache maintenance anywhere.
__device__ inline void group_arrive(unsigned* cnt) {
    __builtin_amdgcn_s_waitcnt(0);     // all prior sc1 stores reached MALL
    __syncthreads();                   // every wave of the block drained
    if (threadIdx.x == 0)
        __hip_atomic_fetch_add(cnt, 1u, __ATOMIC_RELAXED, __HIP_MEMORY_SCOPE_AGENT);
}
__device__ inline void group_wait(const unsigned* cnt, unsigned tgt) {
    if (threadIdx.x == 0) {
        for (unsigned it = 0; it < (1u << 17); ++it) {   // bounded: no hang
            if (ld_coh_u32(cnt) >= tgt) break;
            __builtin_amdgcn_s_sleep(2);
        }
    }
    __syncthreads();
}

// Merged init (R13): every block writebacks+invalidates its XCD L2 (harness
// poison-fill residue); block 0 additionally zeroes the 64 counter slots.
__global__ void initk(unsigned* __restrict__ bar) {
    if (threadIdx.x == 0) __builtin_amdgcn_fence(__ATOMIC_SEQ_CST, "agent");
    __syncthreads();
    if (blockIdx.x == 0) st_coh_u32(&bar[threadIdx.x * 16], 0u);
}

// ============================================================================
// FUSED persistent kernel (R13 body + R14 self-contained producer groups):
// 256 blocks x 1024 threads, group-counter sync, XCD-rectangle swizzle,
// 2-deep GEMM prefetch, phase-2/3 LDS carry-over.
// R14 delta: phase-2/3 identity is DERIVED from the phase-1/4 tile:
//   b = tm>>3, c = tm&7, h = tn   (bijective over the grid)
// => the Cp stripe (c1) and Y stripe (c3) a block consumes are produced by
// exactly the 16 blocks sharing its tm: arrive & wait use the SAME counter
// (self-contained 16-block groups; deadlock-free since arrive precedes wait).
// c2 blocks sharing bh land on one XCD (g1 = b + 2*(h>>2)) -> S/Z L2-local.
// Pure index remap; identical arithmetic; FETCH geometry unchanged.
// ============================================================================
__global__ __launch_bounds__(1024)
void fused(const float* __restrict__ hs, const float* __restrict__ Wq,
           const float* __restrict__ Wk, const float* __restrict__ Wv,
           const float* __restrict__ Wo,
           short* __restrict__ Cp, short* __restrict__ S, float* __restrict__ Z,
           short* __restrict__ Y, float* __restrict__ out,
           unsigned* __restrict__ bar) {
    __shared__ __align__(16) char smem[116736];
    const int tid = threadIdx.x;
    const int bid = blockIdx.x;
    const int lane = tid & 63;
    const int w = tid >> 6;                  // wave 0..15
    const int fm = lane & 15, fk = (lane >> 4) * 8;
    const int crow0 = (lane >> 4) * 4, ccol = lane & 15;

    // XCD-rectangle remap for GEMM phases: XCD g owns 8bm x 4bn tiles.
    const int g1 = bid & 7, i1 = bid >> 3;
    const int tm = ((g1 & 1) << 3) + (i1 & 7);         // bm tile 0..15
    const int tn = ((g1 >> 1) << 2) + (i1 >> 3);       // bn tile 0..15

    // R14: phase-2/3 identity derived from the tile (self-contained groups).
    const int b23 = tm >> 3, c23 = tm & 7, h23 = tn;
    const int bh23 = b23 * 16 + h23;

    // Shared phase-2/3 overlays (FIXED offsets, carried across the c2 sync):
    float (*sKP)[17]          = (float(*)[17])(smem);                    // 0..4352
    unsigned short (*sVT)[72] = (unsigned short(*)[72])(smem + 4352);    // ..13568

    // ---------------- phase 1: gemm_proj  Cp = bf16(hs) @ bf16(W)^T ----------
    {
        short (*sA)[2][64][72] = (short(*)[2][64][72])(smem);            // 36864
        short (*sB)[2][96][72] = (short(*)[2][96][72])(smem + 36864);    // 55296
        float (*sRed)[12]      = (float(*)[12])(smem + 92160);          // 24576
        const int half = tid >> 9;
        const int ht = tid & 511;
        const int wh = w & 7;
        const int bm = tm * 64, bn = tn * 96;
        const int wm = (wh & 3) * 16, wn = (wh >> 2) * 48;
        const int srA = ht >> 3, skA = (ht & 7) * 8;       // 8 shorts/thread
        const int srB = ht >> 2, skB = (ht & 3) * 16;      // 16 shorts/thread
        const int kbase = half * 512;
        f32x4 acc[3] = {};
        const float* pA = hs + (size_t)(bm + srA) * 1024 + kbase + skA;
        const int Rb = bn + (ht < 384 ? srB : 0);
        const float* wsrc = (Rb < 256) ? (Wq + (size_t)Rb * 1024)
                          : (Rb < 512) ? (Wk + (size_t)(Rb - 256) * 1024)
                                       : (Wv + (size_t)(Rb - 512) * 1024);
        const float* pB = wsrc + kbase + skB;
        // --- stage 0 direct to LDS
        {
            float4 t0 = *(const float4*)pA, t1 = *(const float4*)(pA + 4);
            float4 u0, u1, u2, u3;
            if (ht < 384) {
                u0 = *(const float4*)pB;        u1 = *(const float4*)(pB + 4);
                u2 = *(const float4*)(pB + 8);  u3 = *(const float4*)(pB + 12);
            }
            *(bf16x8*)&sA[half][0][srA][skA] = cvt8(t0, t1);
            if (ht < 384) {
                *(bf16x8*)&sB[half][0][srB][skB]     = cvt8(u0, u1);
                *(bf16x8*)&sB[half][0][srB][skB + 8] = cvt8(u2, u3);
            }
        }
        // --- prefetch set A (data[64]) and set B (data[128])
        float4 aA0, aA1, bA0, bA1, bA2, bA3;
        float4 aB0, aB1, bB0, bB1, bB2, bB3;
        aA0 = *(const float4*)(pA + 64);  aA1 = *(const float4*)(pA + 68);
        aB0 = *(const float4*)(pA + 128); aB1 = *(const float4*)(pA + 132);
        if (ht < 384) {
            bA0 = *(const float4*)(pB + 64);  bA1 = *(const float4*)(pB + 68);
            bA2 = *(const float4*)(pB + 72);  bA3 = *(const float4*)(pB + 76);
            bB0 = *(const float4*)(pB + 128); bB1 = *(const float4*)(pB + 132);
            bB2 = *(const float4*)(pB + 136); bB3 = *(const float4*)(pB + 140);
        }
        __syncthreads();
        for (int k0 = 0; k0 < 512; k0 += 128) {
            // ---- sub0: consume LDS buf0 (data[k0]); stage setA -> buf1
            {
                bf16x8 a[2], bfr[2][3];
                #pragma unroll
                for (int ks = 0; ks < 2; ++ks) {
                    a[ks] = *(const bf16x8*)&sA[half][0][wm + fm][ks*32 + fk];
                    #pragma unroll
                    for (int j = 0; j < 3; ++j)
                        bfr[ks][j] = *(const bf16x8*)&sB[half][0][wn + j*16 + fm][ks*32 + fk];
                }
                *(bf16x8*)&sA[half][1][srA][skA] = cvt8(aA0, aA1);
                if (ht < 384) {
                    *(bf16x8*)&sB[half][1][srB][skB]     = cvt8(bA0, bA1);
                    *(bf16x8*)&sB[half][1][srB][skB + 8] = cvt8(bA2, bA3);
                }
                if (k0 + 192 < 512) {
                    const float* pA2 = pA + k0 + 192;
                    aA0 = *(const float4*)pA2; aA1 = *(const float4*)(pA2 + 4);
                    if (ht < 384) {
                        const float* pB2 = pB + k0 + 192;
                        bA0 = *(const float4*)pB2;       bA1 = *(const float4*)(pB2 + 4);
                        bA2 = *(const float4*)(pB2 + 8); bA3 = *(const float4*)(pB2 + 12);
                    }
                }
                #pragma unroll
                for (int ks = 0; ks < 2; ++ks)
                    #pragma unroll
                    for (int j = 0; j < 3; ++j)
                        acc[j] = mfma1(a[ks], bfr[ks][j], acc[j]);
                __syncthreads();
            }
            // ---- sub1: consume LDS buf1 (data[k0+64]); stage setB -> buf0
            {
                bf16x8 a[2], bfr[2][3];
                #pragma unroll
                for (int ks = 0; ks < 2; ++ks) {
                    a[ks] = *(const bf16x8*)&sA[half][1][wm + fm][ks*32 + fk];
                    #pragma unroll
                    for (int j = 0; j < 3; ++j)
                        bfr[ks][j] = *(const bf16x8*)&sB[half][1][wn + j*16 + fm][ks*32 + fk];
                }
                if (k0 + 128 < 512) {
                    *(bf16x8*)&sA[half][0][srA][skA] = cvt8(aB0, aB1);
                    if (ht < 384) {
                        *(bf16x8*)&sB[half][0][srB][skB]     = cvt8(bB0, bB1);
                        *(bf16x8*)&sB[half][0][srB][skB + 8] = cvt8(bB2, bB3);
                    }
                }
                if (k0 + 256 < 512) {
                    const float* pA2 = pA + k0 + 256;
                    aB0 = *(const float4*)pA2; aB1 = *(const float4*)(pA2 + 4);
                    if (ht < 384) {
                        const float* pB2 = pB + k0 + 256;
                        bB0 = *(const float4*)pB2;       bB1 = *(const float4*)(pB2 + 4);
                        bB2 = *(const float4*)(pB2 + 8); bB3 = *(const float4*)(pB2 + 12);
                    }
                }
                #pragma unroll
                for (int ks = 0; ks < 2; ++ks)
                    #pragma unroll
                    for (int j = 0; j < 3; ++j)
                        acc[j] = mfma1(a[ks], bfr[ks][j], acc[j]);
                __syncthreads();
            }
        }
        __syncthreads();
        if (half == 1) {
            #pragma unroll
            for (int j = 0; j < 3; ++j)
                *(f32x4*)&sRed[ht][j * 4] = acc[j];
        }
        __syncthreads();
        if (half == 0) {
            #pragma unroll
            for (int j = 0; j < 3; ++j) {
                f32x4 o = acc[j];
                f32x4 p = *(const f32x4*)&sRed[ht][j * 4];
                #pragma unroll
                for (int r = 0; r < 4; ++r) {
                    short* pcol = Cp + (size_t)(bm + wm + crow0 + r) * 1536
                                     + bn + wn + j*16 + (ccol & ~3);
                    st_quad(pcol, f2bf_rne(o[r] + p[r]), lane);
                }
            }
        }
    }
    group_arrive(&bar[tm * 16]);                       // c1[tm]: stripe done
    group_wait(&bar[tm * 16], 16u);                    // same group: self-sync

    // ---------------- phase 2: chunk_state -----------------------------------
    // sKP (0) and sVT (4352) persist into phase 3. sKT lives at 13568.
    {
        unsigned short (*sKT)[72] = (unsigned short(*)[72])(smem + 13568);
        const int bh = bh23, c = c23;
        const int b = b23, h = h23;
        const int wm = (w & 3) * 16, wn = (w >> 2) * 80;   // valid for w<8
        const int r = (tid & 255) >> 2, q4 = tid & 3;
        const size_t rowbase = (size_t)(b*T + c*CH + r) * 1536;
        if (tid < 256) {
            short4v kv = *(const short4v*)(Cp + rowbase + 256 + h*16 + q4*4);
            const short* pv = Cp + rowbase + 512 + h*HD + q4*16;
            bf16x8 v0 = *(const bf16x8*)pv, v1 = *(const bf16x8*)(pv + 8);
            float4 kf;
            kf.x = bf2f((unsigned short)kv[0]); kf.y = bf2f((unsigned short)kv[1]);
            kf.z = bf2f((unsigned short)kv[2]); kf.w = bf2f((unsigned short)kv[3]);
            *(float4*)&sKP[r][q4*4] = kf;
            #pragma unroll
            for (int e = 0; e < 8; ++e) {
                sVT[q4*16 + e][r]     = (unsigned short)v0[e];
                sVT[q4*16 + 8 + e][r] = (unsigned short)v1[e];
            }
        }
        __syncthreads();
        {   // transposed features, 4x parallel
            const int r3 = tid >> 4, sub = tid & 15;
            const int q4t = sub & 3, gh = sub >> 2;
            const float* x = sKP[r3];
            #pragma unroll
            for (int dd = 0; dd < 10; ++dd) {
                const int D = q4t*40 + gh*10 + dd;
                sKT[D][r3] = f2bf_rne(featval(x, D));
            }
        }
        __syncthreads();
        if (tid < DP) {
            float zz = 0.f;
            #pragma unroll
            for (int blk = 0; blk < 8; ++blk) {
                bf16x8 v = *(const bf16x8*)&sKT[tid][blk*8];
                #pragma unroll
                for (int e = 0; e < 8; ++e) zz += bf2f((unsigned short)v[e]);
            }
            st_coh_u32((unsigned*)(Z + ((size_t)(bh*NC + c)) * DP + tid),
                       __float_as_uint(zz));
        }
        if (w < 8) {
            f32x4 acc2[5] = {};
            #pragma unroll
            for (int k0 = 0; k0 < 64; k0 += 32) {
                bf16x8 a = *(const bf16x8*)&sVT[wm + fm][k0 + fk];
                #pragma unroll
                for (int j = 0; j < 5; ++j) {
                    bf16x8 bv = *(const bf16x8*)&sKT[wn + j*16 + fm][k0 + fk];
                    acc2[j] = mfma1(a, bv, acc2[j]);
                }
            }
            short* Sb = S + ((size_t)(bh*NC + c)) * CH * DP;
            #pragma unroll
            for (int j = 0; j < 5; ++j)
                #pragma unroll
                for (int rr = 0; rr < 4; ++rr) {
                    short* pcol = Sb + (size_t)(wm + crow0 + rr) * DP
                                     + wn + j*16 + (ccol & ~3);
                    st_quad(pcol, f2bf_rne(acc2[j][rr]), lane);
                }
        }
    }
    group_arrive(&bar[(16 + bh23) * 16]);              // c2[bh]: S/Z chunk done
    group_wait(&bar[(16 + bh23) * 16], 8u);            // need all 8 chunks of bh

    // ---------------- phase 3: chunk_out (reuses sKP & sVT from phase 2) -----
    {
        float (*sQP)[17]          = (float(*)[17])(smem + 13568);            // 4352
        unsigned short (*sQf)[168]= (unsigned short(*)[168])(smem + 17920);  // 21504
        unsigned short (*sKf)[168]= (unsigned short(*)[168])(smem + 39424);  // 21504
        unsigned short (*sPb)[168]= (unsigned short(*)[168])(smem + 60928);  // 21504
        unsigned short (*sAb)[72] = (unsigned short(*)[72])(smem + 82432);   // 9216
        float* sZp  = (float*)(smem + 91648);
        float* sDen = (float*)(smem + 92288);
        const int bh = bh23, c = c23;
        const int b = b23, h = h23;
        const int wm = (w & 3) * 16, wn = (w >> 2) * 16;
        const int r = (tid & 255) >> 2, q4 = tid & 3;
        const size_t rowbase = (size_t)(b*T + c*CH + r) * 1536;
        f32x4 accA = {}, accI = {};
        if (tid < 256) {
            short4v qv = *(const short4v*)(Cp + rowbase + h*16 + q4*4);
            float4 qf;
            qf.x = bf2f((unsigned short)qv[0]); qf.y = bf2f((unsigned short)qv[1]);
            qf.z = bf2f((unsigned short)qv[2]); qf.w = bf2f((unsigned short)qv[3]);
            *(float4*)&sQP[r][q4*4] = qf;
            if (tid < DP) {
                // Z-prefix: all 7 loads unconditional (c2[bh]==8 -> race-free),
                // value-masked accumulate.
                float zv[7];
                #pragma unroll
                for (int cc = 0; cc < 7; ++cc)
                    zv[cc] = Z[((size_t)(bh*NC + cc)) * DP + tid];
                float zz = 0.f;
                #pragma unroll
                for (int cc = 0; cc < 7; ++cc)
                    zz += (cc < c) ? zv[cc] : 0.f;
                sZp[tid] = zz;
            }
        }
        __syncthreads();
        {   // row-major features: sub = dst*8 + q4f*2 + gh (sKP carried over)
            const int r3 = tid >> 4, sub = tid & 15;
            const int dst = sub >> 3, q4f = (sub >> 1) & 3, gh = sub & 1;
            const float* x = dst ? sKP[r3] : sQP[r3];
            unsigned short* drow = dst ? sKf[r3] : sQf[r3];
            #pragma unroll
            for (int g = 0; g < 5; ++g) {
                const int gg = gh*5 + g;
                short4v s;
                #pragma unroll
                for (int e = 0; e < 4; ++e)
                    s[e] = (short)f2bf_rne(featval(x, q4f*40 + gg*4 + e));
                *(short4v*)(drow + q4f*40 + gg*4) = s;
            }
        }
        {   // S-prefix sums, 1024 threads, unconditional 7-load batches.
            for (int e = tid; e < 1280; e += 1024) {
                const int d = e / 20, D8 = (e % 20) * 8;
                bf16x8 raw[7];
                #pragma unroll
                for (int cc = 0; cc < 7; ++cc)
                    raw[cc] = *(const bf16x8*)(S + (((size_t)(bh*NC + cc)) * CH + d) * DP + D8);
                float a8[8] = {};
                #pragma unroll
                for (int cc = 0; cc < 7; ++cc) {
                    #pragma unroll
                    for (int e2 = 0; e2 < 8; ++e2)
                        a8[e2] += (cc < c) ? bf2f((unsigned short)raw[cc][e2]) : 0.f;
                }
                bf16x8 o;
                #pragma unroll
                for (int e2 = 0; e2 < 8; ++e2) o[e2] = (short)f2bf_rne(a8[e2]);
                *(bf16x8*)&sPb[d][D8] = o;
            }
        }
        __syncthreads();
        {   // MFMA stage 1: A = Qf.Kf^T, I = Qf.Pb^T
            for (int k0 = 0; k0 < DP; k0 += 32) {
                bf16x8 qv = *(const bf16x8*)&sQf[wm + fm][k0 + fk];
                bf16x8 kv = *(const bf16x8*)&sKf[wn + fm][k0 + fk];
                bf16x8 pv = *(const bf16x8*)&sPb[wn + fm][k0 + fk];
                accA = mfma1(qv, kv, accA);
                accI = mfma1(qv, pv, accI);
            }
        }
        if (tid < 256) {   // denominator dot with Z-prefix
            float dp = 0.f;
            #pragma unroll
            for (int g = 0; g < 5; ++g) {
                bf16x8 v = *(const bf16x8*)&sQf[r][q4*40 + g*8];
                #pragma unroll
                for (int e = 0; e < 8; ++e)
                    dp += bf2f((unsigned short)v[e]) * sZp[q4*40 + g*8 + e];
            }
            dp += __shfl_xor(dp, 1);
            dp += __shfl_xor(dp, 2);
            if (q4 == 0) sDen[r] = dp;
        }
        {   // causal-mask A into LDS (each wave its 16x16 tile)
            #pragma unroll
            for (int rr = 0; rr < 4; ++rr) {
                const int t_ = wm + crow0 + rr, s_ = wn + ccol;
                sAb[t_][s_] = (s_ <= t_) ? f2bf_rne(accA[rr]) : 0;
            }
        }
        __syncthreads();
        if (tid < 256) {   // row-sum of causal A into denominator
            float rs = 0.f;
            bf16x8 v0 = *(const bf16x8*)&sAb[r][q4*16];
            bf16x8 v1 = *(const bf16x8*)&sAb[r][q4*16 + 8];
            #pragma unroll
            for (int e = 0; e < 8; ++e)
                rs += bf2f((unsigned short)v0[e]) + bf2f((unsigned short)v1[e]);
            rs += __shfl_xor(rs, 1);
            rs += __shfl_xor(rs, 2);
            if (q4 == 0) sDen[r] += rs;
        }
        __syncthreads();
        {   // MFMA stage 2: I += Ab.VT^T (sVT carried over) ; write Y
            #pragma unroll
            for (int k0 = 0; k0 < 64; k0 += 32) {
                bf16x8 a = *(const bf16x8*)&sAb[wm + fm][k0 + fk];
                bf16x8 bv = *(const bf16x8*)&sVT[wn + fm][k0 + fk];
                accI = mfma1(a, bv, accI);
            }
            #pragma unroll
            for (int rr = 0; rr < 4; ++rr) {
                const int t_ = wm + crow0 + rr;
                const float inv = 1.f / (sDen[t_] + 1e-12f);
                const size_t grow = (size_t)(b*T + c*CH + t_) * 1024 + h*HD;
                short* pcol = Y + grow + wn + (ccol & ~3);
                st_quad(pcol, f2bf_rne(accI[rr] * inv), lane);
            }
        }
    }
    group_arrive(&bar[(48 + tm) * 16]);                // c3[tm]: Y rows done
    // phase-4 Wo prefetch (all 3 chunks): pure input, load BEFORE the wait.
    const int p4_half = tid >> 9;
    const int p4_ht = tid & 511;
    const int p4_bn = tn * 64;
    const int p4_srow = p4_ht >> 3, p4_skq = (p4_ht & 7) * 8;
    const float* p4_pB = Wo + (size_t)(p4_bn + p4_srow) * 1024 + p4_half * 512 + p4_skq;
    float4 w00 = *(const float4*)p4_pB,         w01 = *(const float4*)(p4_pB + 4);
    float4 wA0 = *(const float4*)(p4_pB + 64),  wA1 = *(const float4*)(p4_pB + 68);
    float4 wB0 = *(const float4*)(p4_pB + 128), wB1 = *(const float4*)(p4_pB + 132);
    group_wait(&bar[(48 + tm) * 16], 16u);             // same group: self-sync

    // ---------------- phase 4: gemm_out  out = Y @ bf16(Wo)^T ----------------
    // 2-deep prefetch mirror of phase 1.
    {
        short (*sA)[2][64][72] = (short(*)[2][64][72])(smem);
        short (*sB)[2][64][72] = (short(*)[2][64][72])(smem + 36864);
        float (*sRed)[8]       = (float(*)[8])(smem + 73728);           // 16384
        const int half = p4_half;
        const int ht = p4_ht;
        const int wh = w & 7;
        const int bm = tm * 64, bn = p4_bn;
        const int wm = (wh & 3) * 16, wn = (wh >> 2) * 32;
        const int srow = p4_srow, skq = p4_skq;
        const int kbase = half * 512;
        f32x4 acc[2] = {};
        const short* pA = Y + (size_t)(bm + srow) * 1024 + kbase + skq;
        const float* pB = p4_pB;
        // issue all 3 Y chunk loads together (one exposed MALL latency)
        bf16x8 y0  = *(const bf16x8*)pA;
        bf16x8 yA  = *(const bf16x8*)(pA + 64);
        bf16x8 yB  = *(const bf16x8*)(pA + 128);
        float4 qbA0 = wA0, qbA1 = wA1;
        float4 qbB0 = wB0, qbB1 = wB1;
        *(bf16x8*)&sA[half][0][srow][skq] = y0;
        *(bf16x8*)&sB[half][0][srow][skq] = cvt8(w00, w01);
        __syncthreads();
        for (int k0 = 0; k0 < 512; k0 += 128) {
            // ---- sub0: consume buf0 (data[k0]); stage setA -> buf1
            {
                bf16x8 a[2], b2[2][2];
                #pragma unroll
                for (int ks = 0; ks < 2; ++ks) {
                    a[ks] = *(const bf16x8*)&sA[half][0][wm + fm][ks*32 + fk];
                    #pragma unroll
                    for (int j = 0; j < 2; ++j)
                        b2[ks][j] = *(const bf16x8*)&sB[half][0][wn + j*16 + fm][ks*32 + fk];
                }
                *(bf16x8*)&sA[half][1][srow][skq] = yA;
                *(bf16x8*)&sB[half][1][srow][skq] = cvt8(qbA0, qbA1);
                if (k0 + 192 < 512) {
                    yA = *(const bf16x8*)(pA + k0 + 192);
                    const float* pB2 = pB + k0 + 192;
                    qbA0 = *(const float4*)pB2; qbA1 = *(const float4*)(pB2 + 4);
                }
                #pragma unroll
                for (int ks = 0; ks < 2; ++ks)
                    #pragma unroll
                    for (int j = 0; j < 2; ++j)
                        acc[j] = mfma1(a[ks], b2[ks][j], acc[j]);
                __syncthreads();
            }
            // ---- sub1: consume buf1 (data[k0+64]); stage setB -> buf0
            {
                bf16x8 a[2], b2[2][2];
                #pragma unroll
                for (int ks = 0; ks < 2; ++ks) {
                    a[ks] = *(const bf16x8*)&sA[half][1][wm + fm][ks*32 + fk];
                    #pragma unroll
                    for (int j = 0; j < 2; ++j)
                        b2[ks][j] = *(const bf16x8*)&sB[half][1][wn + j*16 + fm][ks*32 + fk];
                }
                if (k0 + 128 < 512) {
                    *(bf16x8*)&sA[half][0][srow][skq] = yB;
                    *(bf16x8*)&sB[half][0][srow][skq] = cvt8(qbB0, qbB1);
                }
                if (k0 + 256 < 512) {
                    yB = *(const bf16x8*)(pA + k0 + 256);
                    const float* pB2 = pB + k0 + 256;
                    qbB0 = *(const float4*)pB2; qbB1 = *(const float4*)(pB2 + 4);
                }
                #pragma unroll
                for (int ks = 0; ks < 2; ++ks)
                    #pragma unroll
                    for (int j = 0; j < 2; ++j)
                        acc[j] = mfma1(a[ks], b2[ks][j], acc[j]);
                __syncthreads();
            }
        }
        __syncthreads();
        if (half == 1) {
            #pragma unroll
            for (int j = 0; j < 2; ++j)
                *(f32x4*)&sRed[ht][j * 4] = acc[j];
        }
        __syncthreads();
        if (half == 0) {
            #pragma unroll
            for (int j = 0; j < 2; ++j) {
                f32x4 p = *(const f32x4*)&sRed[ht][j * 4];
                #pragma unroll
                for (int r = 0; r < 4; ++r)
                    out[(size_t)(bm + wm + crow0 + r) * 1024 + bn + wn + j*16 + ccol] =
                        acc[j][r] + p[r];
            }
        }
    }
}

extern "C" void kernel_launch(void* const* d_in, const int* in_sizes, int n_in,
                              void* d_out, int out_size, void* d_ws, size_t ws_size,
                              hipStream_t stream) {
    const float* hs = (const float*)d_in[0];
    const float* Wq = (const float*)d_in[1];
    const float* Wk = (const float*)d_in[2];
    const float* Wv = (const float*)d_in[3];
    const float* Wo = (const float*)d_in[4];
    float* out = (float*)d_out;

    char* p = (char*)d_ws;
    short* Cp  = (short*)p; p += (size_t)1024*1536*2;
    short* S   = (short*)p; p += (size_t)32*NC*CH*DP*2;
    float* Z   = (float*)p; p += (size_t)32*NC*DP*4;
    short* Y   = (short*)p; p += (size_t)1048576*2;
    unsigned* bar = (unsigned*)p; p += 4096;

    initk<<<dim3(64), dim3(64), 0, stream>>>(bar);
    fused<<<dim3(256), dim3(1024), 0, stream>>>(hs, Wq, Wk, Wv, Wo,
                                                Cp, S, Z, Y, out, bar);
}